// Round 13
// baseline (333.419 us; speedup 1.0000x reference)
//
#include <hip/hip_runtime.h>
#include <hip/hip_bf16.h>

typedef unsigned short u16;
typedef __attribute__((ext_vector_type(4))) float f32x4;
typedef __attribute__((ext_vector_type(8))) short s16x8;
typedef __attribute__((ext_vector_type(4))) short s16x4;
typedef __attribute__((ext_vector_type(8))) __bf16 bf16x8;

#define NTOK 4096
#define DMODEL 1024
#define DFF 4096
#define NH 16
#define TSEQ 1024

#define SBAR() do { asm volatile("" ::: "memory"); __builtin_amdgcn_s_barrier(); asm volatile("" ::: "memory"); } while (0)

// ---------- helpers ----------

__device__ __forceinline__ u16 f2b_hw(float f) {
  union { __bf16 h; u16 u; } cv;
  cv.h = (__bf16)f;
  return cv.u;
}

__device__ __forceinline__ f32x4 mfma16(s16x8 a, s16x8 b, f32x4 c) {
  return __builtin_amdgcn_mfma_f32_16x16x32_bf16((bf16x8)a, (bf16x8)b, c, 0, 0, 0);
}

__device__ __forceinline__ void gload16(const u16* g, u16* l) {
  __builtin_amdgcn_global_load_lds(
      (const __attribute__((address_space(1))) unsigned int*)g,
      (__attribute__((address_space(3))) unsigned int*)l, 16, 0, 0);
}

// natural-layout fragment from a swizzled 64-elem-row LDS tile
__device__ __forceinline__ s16x8 ld8s(const u16* t, int row, int eoff) {
  int rx = row & 7;
  const u16* p1 = t + row * 64 + ((((eoff >> 3) ^ rx) << 3) | (eoff & 7));
  const u16* p2 = t + row * 64 + (((((eoff + 16) >> 3) ^ rx) << 3) | (eoff & 7));
  s16x4 lo = *(const s16x4*)p1;
  s16x4 hi = *(const s16x4*)p2;
  s16x8 r;
  r[0] = lo[0]; r[1] = lo[1]; r[2] = lo[2]; r[3] = lo[3];
  r[4] = hi[0]; r[5] = hi[1]; r[6] = hi[2]; r[7] = hi[3];
  return r;
}

// k-permuted (contiguous 16B, uniform permutation) fragment from swizzled tile
__device__ __forceinline__ s16x8 ld16s(const u16* t, int row, int ch) {
  return *(const s16x8*)(t + row * 64 + ((ch ^ (row & 7)) << 3));
}

// ---------- fused fp32 -> bf16 converts (11 segments, one kernel) ----------

struct F2B {
  const float* s[11];
  u16* d[11];
};

__global__ __launch_bounds__(256) void f2b_all(F2B a) {
  int bid = blockIdx.x;
  int seg, boff;
  if (bid < 8192) { seg = bid >> 10; boff = bid & 1023; }
  else { int j = bid - 8192; seg = 8 + (j >> 12); boff = j & 4095; }
  size_t i = ((size_t)boff * 256 + threadIdx.x) * 4;
  float4 v = *(const float4*)(a.s[seg] + i);
  ushort4 o = make_ushort4(f2b_hw(v.x), f2b_hw(v.y), f2b_hw(v.z), f2b_hw(v.w));
  *(ushort4*)(a.d[seg] + i) = o;
}

// ---------- LayerNorm ----------

__global__ __launch_bounds__(256) void ln_kernel(const float* __restrict__ x,
                                                 const float* __restrict__ w,
                                                 const float* __restrict__ b,
                                                 u16* __restrict__ out) {
  int row = blockIdx.x;
  int t = threadIdx.x;
  const float* xr = x + (size_t)row * DMODEL;
  float4 v = *(const float4*)(xr + t * 4);
  float s = v.x + v.y + v.z + v.w;
#pragma unroll
  for (int off = 1; off < 64; off <<= 1) s += __shfl_xor(s, off);
  __shared__ float red[8];
  int wid = t >> 6, lane = t & 63;
  if (lane == 0) red[wid] = s;
  __syncthreads();
  float mean = (red[0] + red[1] + red[2] + red[3]) * (1.0f / 1024.0f);
  float dx = v.x - mean, dy = v.y - mean, dz = v.z - mean, dw = v.w - mean;
  float ss = dx * dx + dy * dy + dz * dz + dw * dw;
#pragma unroll
  for (int off = 1; off < 64; off <<= 1) ss += __shfl_xor(ss, off);
  if (lane == 0) red[4 + wid] = ss;
  __syncthreads();
  float sst = red[4] + red[5] + red[6] + red[7];
  float inv = 1.0f / (sqrtf(sst / 1023.0f) + 1e-6f);
  float4 wv = *(const float4*)(w + t * 4);
  float4 bv = *(const float4*)(b + t * 4);
  ushort4 o = make_ushort4(f2b_hw(wv.x * dx * inv + bv.x), f2b_hw(wv.y * dy * inv + bv.y),
                           f2b_hw(wv.z * dz * inv + bv.z), f2b_hw(wv.w * dw * inv + bv.w));
  *(ushort4*)(out + (size_t)row * DMODEL + t * 4) = o;
}

// ---------- 256x256x64 8-phase GEMM (T2+T3+T4+T5), bf16 out (+RELU) ----------
// Round-12 proven: 0 bank conflicts, 45.0us on FF1 (vs 48.4 2-phase).

template <bool RELU>
__global__ __launch_bounds__(512, 2) void gemm256(const u16* __restrict__ A,
                                                  const u16* __restrict__ W,
                                                  const float* __restrict__ bias,
                                                  u16* __restrict__ out,
                                                  int M, int N, int K, int ld,
                                                  int gx) {
  __shared__ u16 As[2][2][8192];
  __shared__ u16 Bs[2][2][8192];
  const int nwg = gridDim.x, qch = nwg >> 3, bid = blockIdx.x;
  const int wg = (bid & 7) * qch + (bid >> 3);
  const int bx = wg % gx, by = wg / gx;
  const int m0 = by * 256, n0 = bx * 256;
  const int tid = threadIdx.x;
  const int wid = tid >> 6, lane = tid & 63;
  const int wr = wid >> 2, wc = wid & 3;
  const int lhi = lane >> 4, llo = lane & 15;
  f32x4 acc[8][4] = {};
  const int srow = tid >> 2;
  const int ssw = ((tid & 3) ^ ((srow >> 1) & 3)) << 3;  // pre-swizzled source chunk

  auto unitA = [&](int kt, int kh) {
    const u16* p = A + (size_t)(m0 + srow) * ld + kt * 64 + kh * 32 + ssw;
    gload16(p, &As[kt & 1][kh][tid * 8]);
    gload16(p + (size_t)128 * ld, &As[kt & 1][kh][4096 + tid * 8]);
  };
  auto unitB = [&](int kt, int kh) {
    const u16* p = W + (size_t)(n0 + srow) * ld + kt * 64 + kh * 32 + ssw;
    gload16(p, &Bs[kt & 1][kh][tid * 8]);
    gload16(p + (size_t)128 * ld, &Bs[kt & 1][kh][4096 + tid * 8]);
  };

  s16x8 bf[4];
  auto phase = [&](int d, int ch, int kh, bool loadB, auto stfn, int vm) {
    s16x8 af[4];
#pragma unroll
    for (int fm = 0; fm < 4; fm++) {
      int row = wr * 128 + ch * 64 + fm * 16 + llo;
      af[fm] = *(const s16x8*)(&As[d][kh][row * 32 + ((lhi ^ ((row >> 1) & 3)) << 3)]);
    }
    if (loadB) {
#pragma unroll
      for (int fn = 0; fn < 4; fn++) {
        int row = wc * 64 + fn * 16 + llo;
        bf[fn] = *(const s16x8*)(&Bs[d][kh][row * 32 + ((lhi ^ ((row >> 1) & 3)) << 3)]);
      }
    }
    stfn();
    SBAR();
    __builtin_amdgcn_s_setprio(1);
#pragma unroll
    for (int fm = 0; fm < 4; fm++)
#pragma unroll
      for (int fn = 0; fn < 4; fn++)
        acc[ch * 4 + fm][fn] = mfma16(af[fm], bf[fn], acc[ch * 4 + fm][fn]);
    __builtin_amdgcn_s_setprio(0);
    if (vm == 8) asm volatile("s_waitcnt vmcnt(8)" ::: "memory");
    else if (vm == 4) asm volatile("s_waitcnt vmcnt(4)" ::: "memory");
    else if (vm == 0) asm volatile("s_waitcnt vmcnt(0)" ::: "memory");
    SBAR();
  };

  // prologue: 6 units (t0 full + t1 k0)
  unitA(0, 0); unitB(0, 0); unitA(0, 1); unitB(0, 1); unitA(1, 0); unitB(1, 0);
  asm volatile("s_waitcnt vmcnt(8)" ::: "memory");
  SBAR();

  const int NPAIR = K >> 7;
#pragma unroll 1
  for (int i = 0; i < NPAIR; ++i) {
    const int tb = 2 * i + 1, tc = 2 * i + 2, td = 2 * i + 3;
    const bool nx = (i + 1 < NPAIR);
    phase(0, 0, 0, true,  [&] { unitA(tb, 1); }, -1);
    phase(0, 1, 0, false, [&] { unitB(tb, 1); }, 8);
    phase(0, 1, 1, true,  [&] { if (nx) unitA(tc, 0); }, -1);
    phase(0, 0, 1, false, [&] { if (nx) unitB(tc, 0); }, nx ? 8 : 4);
    phase(1, 0, 0, true,  [&] { if (nx) unitA(tc, 1); }, -1);
    phase(1, 1, 0, false, [&] { if (nx) unitB(tc, 1); }, nx ? 8 : 0);
    phase(1, 1, 1, true,  [&] { if (nx) unitA(td, 0); }, -1);
    phase(1, 0, 1, false, [&] { if (nx) unitB(td, 0); }, nx ? 8 : -1);
  }

#pragma unroll
  for (int ch = 0; ch < 2; ch++)
#pragma unroll
    for (int fm = 0; fm < 4; fm++)
#pragma unroll
      for (int fn = 0; fn < 4; fn++) {
        int r0 = m0 + wr * 128 + ch * 64 + fm * 16 + lhi * 4;
        int c = n0 + wc * 64 + fn * 16 + llo;
        float bv = bias[c];
#pragma unroll
        for (int i2 = 0; i2 < 4; i2++) {
          float v = acc[ch * 4 + fm][fn][i2] + bv;
          if (RELU) v = fmaxf(v, 0.0f);
          out[(size_t)(r0 + i2) * N + c] = f2b_hw(v);
        }
      }
  (void)M;
}

// ---------- 2-phase 512-thread GEMM (proven round-7/10 config) ----------
// MODE 0: fp32 out [M,N] (+resid); MODE 1: bf16 [M,N] (+RELU);
// MODE 2: packed heads (QBUF scaled, VBUF transposed);
// MODE 3 (SPLITK): atomicAdd fp32 into outp (bias added by half 0 only).

template <int MODE, bool RELU, bool SPLITK = false, int QBUF = -1, int VBUF = -1>
__global__ __launch_bounds__(512) void gemm_bt(const u16* __restrict__ A,
                                               const u16* __restrict__ W,
                                               const float* __restrict__ b0,
                                               const float* __restrict__ b1,
                                               const float* __restrict__ b2,
                                               const float* resid, void* outp,
                                               int M, int N, int K, int ld,
                                               int gx) {
  __shared__ u16 As[2][128 * 64];
  __shared__ u16 Bs[2][128 * 64];
  const int nwg = gridDim.x;
  const int qch = nwg >> 3;
  const int bid = blockIdx.x;
  int wg = (bid & 7) * qch + (bid >> 3);
  int half = 0;
  if (SPLITK) { half = wg & 1; wg >>= 1; }
  const int bx = wg % gx, by = wg / gx;
  const int m0 = by * 128, n0 = bx * 128;
  if (SPLITK) { A += (size_t)half * K; W += (size_t)half * K; }
  const int tid = threadIdx.x;
  const int wid = tid >> 6, lane = tid & 63;
  const int wr = wid >> 2, wc = wid & 3;
  const int lhi = lane >> 4, llo = lane & 15;
  f32x4 acc[4][2] = {};
  const int sr = tid >> 3, sc = tid & 7;
  const int srcoff = (sc ^ (sr & 7)) << 3;

  auto stage = [&](int kk, int buf) {
    const u16* Ap = A + (size_t)(m0 + sr) * ld + kk + srcoff;
    gload16(Ap, &As[buf][tid * 8]);
    gload16(Ap + (size_t)64 * ld, &As[buf][4096 + tid * 8]);
    const u16* Wp = W + (size_t)(n0 + sr) * ld + kk + srcoff;
    gload16(Wp, &Bs[buf][tid * 8]);
    gload16(Wp + (size_t)64 * ld, &Bs[buf][4096 + tid * 8]);
  };

  stage(0, 0);
  __syncthreads();

  for (int k0 = 0; k0 < K; k0 += 64) {
    int cur = (k0 >> 6) & 1;
    if (k0 + 64 < K) stage(k0 + 64, cur ^ 1);
#pragma unroll
    for (int ks8 = 0; ks8 < 8; ks8 += 4) {
      s16x8 af[4], bfr[2];
#pragma unroll
      for (int f = 0; f < 4; f++) af[f] = ld16s(&As[cur][0], wr * 64 + f * 16 + llo, ks8 + lhi);
#pragma unroll
      for (int g = 0; g < 2; g++) bfr[g] = ld16s(&Bs[cur][0], wc * 32 + g * 16 + llo, ks8 + lhi);
#pragma unroll
      for (int f = 0; f < 4; f++)
#pragma unroll
        for (int g = 0; g < 2; g++) acc[f][g] = mfma16(af[f], bfr[g], acc[f][g]);
    }
    __syncthreads();
  }

#pragma unroll
  for (int fm = 0; fm < 4; fm++) {
#pragma unroll
    for (int fn = 0; fn < 2; fn++) {
      int c = n0 + wc * 32 + fn * 16 + llo;
      const int r0 = m0 + wr * 64 + fm * 16 + lhi * 4;
      if (MODE == 2) {
        int buf = c >> 10, cc = c & 1023;
        int hh = cc >> 6, d = cc & 63;
        int bb = r0 >> 10, t0 = r0 & 1023;
        const float* bias = (buf == 0) ? b0 : ((buf == 1) ? b1 : b2);
        float bv = bias[cc];
        float v4[4];
#pragma unroll
        for (int i = 0; i < 4; i++) {
          float v = acc[fm][fn][i] + bv;
          if (buf == QBUF) v *= 0.125f;
          v4[i] = v;
        }
        if (buf == VBUF) {
          ushort4 st = make_ushort4(f2b_hw(v4[0]), f2b_hw(v4[1]), f2b_hw(v4[2]), f2b_hw(v4[3]));
          *(ushort4*)(&((u16*)outp)[(size_t)buf * 4194304 +
                                    (((size_t)(bb * NH + hh)) * 64 + d) * TSEQ + t0]) = st;
        } else {
#pragma unroll
          for (int i = 0; i < 4; i++)
            ((u16*)outp)[(size_t)buf * 4194304 +
                         (((size_t)(bb * NH + hh)) * TSEQ + t0 + i) * 64 + d] = f2b_hw(v4[i]);
        }
      } else if (MODE == 3) {
        float bv = (half == 0 && b0) ? b0[c] : 0.0f;
#pragma unroll
        for (int i = 0; i < 4; i++) {
          float v = acc[fm][fn][i] + bv;
          atomicAdd((float*)outp + (size_t)(r0 + i) * N + c, v);
        }
      } else {
        float bv = b0 ? b0[c] : 0.0f;
#pragma unroll
        for (int i = 0; i < 4; i++) {
          int r = r0 + i;
          float v = acc[fm][fn][i] + bv;
          if (resid) v += resid[(size_t)r * N + c];
          if (RELU) v = fmaxf(v, 0.0f);
          if (MODE == 0) {
            ((float*)outp)[(size_t)r * N + c] = v;
          } else {
            ((u16*)outp)[(size_t)r * N + c] = f2b_hw(v);
          }
        }
      }
    }
  }
}

// ---------- flash attention (round-10 proven, causal-balanced) ----------

template <bool CAUSAL>
__global__ __launch_bounds__(256) void attn_kernel(const u16* __restrict__ Qg,
                                                   const u16* __restrict__ Kg,
                                                   const u16* __restrict__ Vt,
                                                   u16* __restrict__ Og) {
  const int bid = blockIdx.x;
  const int wg = (bid & 7) * 64 + (bid >> 3);
  const int bh = wg >> 3;
  const int qblk = (wg & 7) ^ (CAUSAL ? 7 * ((bid >> 8) & 1) : 0);
  const int b = bh >> 4, h = bh & 15;
  const int q0 = qblk * 128;
  const int tid = threadIdx.x, wid = tid >> 6, lane = tid & 63;
  const int lhi = lane >> 4, llo = lane & 15;
  __shared__ u16 Ks[2][4096];
  __shared__ u16 Vs[2][4096];

  const int qr = q0 + wid * 16 + llo;
  const u16* qp0 = Qg + ((size_t)bh * TSEQ + qr) * 64;
  s16x8 qf[2][2];
  qf[0][0] = *(const s16x8*)(qp0 + 8 * lhi);
  qf[0][1] = *(const s16x8*)(qp0 + 8 * (4 + lhi));
  qf[1][0] = *(const s16x8*)(qp0 + 4096 + 8 * lhi);
  qf[1][1] = *(const s16x8*)(qp0 + 4096 + 8 * (4 + lhi));

  f32x4 oacc[2][4] = {};
  float mrun[2] = {-1.0e30f, -1.0e30f}, lrun[2] = {0.0f, 0.0f};
  const size_t kvb = (size_t)bh * (TSEQ * 64);
  const int nt = CAUSAL ? ((q0 + 128) >> 6) : (TSEQ >> 6);

  const int srow = tid >> 3;
  const int ssw = ((tid & 7) ^ (srow & 7)) << 3;

  auto stageK = [&](int s0, int buf) {
    const u16* kb = Kg + kvb + (size_t)s0 * 64;
    gload16(kb + (size_t)srow * 64 + ssw, &Ks[buf][tid * 8]);
    gload16(kb + (size_t)(32 + srow) * 64 + ssw, &Ks[buf][2048 + tid * 8]);
  };
  auto stageV = [&](int s0, int buf) {
    const u16* vb2 = Vt + kvb + s0;
    gload16(vb2 + (size_t)srow * TSEQ + ssw, &Vs[buf][tid * 8]);
    gload16(vb2 + (size_t)(32 + srow) * TSEQ + ssw, &Vs[buf][2048 + tid * 8]);
  };

  stageK(0, 0);
  stageV(0, 0);
  __syncthreads();

  for (int t = 0; t < nt; ++t) {
    int cur = t & 1;
    if (t + 1 < nt) {
      stageK((t + 1) * 64, cur ^ 1);
      stageV((t + 1) * 64, cur ^ 1);
    }
    int s0 = t * 64;
    const bool act0 = !CAUSAL || (s0 < q0 + 64);

    s16x8 kf[4][2];
#pragma unroll
    for (int g = 0; g < 4; g++) {
      kf[g][0] = ld16s(&Ks[cur][0], g * 16 + llo, lhi);
      kf[g][1] = ld16s(&Ks[cur][0], g * 16 + llo, 4 + lhi);
    }

    s16x8 pf[2][2];
#pragma unroll
    for (int s = 0; s < 2; s++) {
      if (s == 0 && !act0) continue;
      f32x4 sacc[4] = {};
#pragma unroll
      for (int g = 0; g < 4; g++) {
        sacc[g] = mfma16(kf[g][0], qf[s][0], sacc[g]);
        sacc[g] = mfma16(kf[g][1], qf[s][1], sacc[g]);
      }
      const int qrow = qr + s * 64;
      const bool diag = CAUSAL && (s0 == q0 + s * 64);
      float sv[16];
      float pmax = -1.0e30f;
#pragma unroll
      for (int g = 0; g < 4; g++)
#pragma unroll
        for (int i = 0; i < 4; i++) {
          float sc = sacc[g][i];
          if (diag) {
            int kv = s0 + g * 16 + lhi * 4 + i;
            if (kv > qrow) sc = -1.0e9f;
          }
          sv[g * 4 + i] = sc;
          pmax = fmaxf(pmax, sc);
        }
      pmax = fmaxf(pmax, __shfl_xor(pmax, 16));
      pmax = fmaxf(pmax, __shfl_xor(pmax, 32));
      if (!__all(pmax - mrun[s] <= 8.0f)) {
        float mnew = fmaxf(mrun[s], pmax);
        float alpha = __expf(mrun[s] - mnew);
        lrun[s] *= alpha;
#pragma unroll
        for (int g = 0; g < 4; g++) {
          oacc[s][g][0] *= alpha; oacc[s][g][1] *= alpha;
          oacc[s][g][2] *= alpha; oacc[s][g][3] *= alpha;
        }
        mrun[s] = mnew;
      }
      float ls = 0.0f;
#pragma unroll
      for (int j = 0; j < 16; j++) {
        float p = __expf(sv[j] - mrun[s]);
        ls += p;
        pf[s][j >> 3][((j >> 2) & 1) * 4 + (j & 3)] = (short)f2b_hw(p);
      }
      ls += __shfl_xor(ls, 16);
      ls += __shfl_xor(ls, 32);
      lrun[s] += ls;
    }

#pragma unroll
    for (int dg = 0; dg < 4; dg++) {
      int row = dg * 16 + llo;
      s16x8 vf0 = ld8s(&Vs[cur][0], row, lhi * 4);
      s16x8 vf1 = ld8s(&Vs[cur][0], row, 32 + lhi * 4);
      if (act0) {
        oacc[0][dg] = mfma16(vf0, pf[0][0], oacc[0][dg]);
        oacc[0][dg] = mfma16(vf1, pf[0][1], oacc[0][dg]);
      }
      oacc[1][dg] = mfma16(vf0, pf[1][0], oacc[1][dg]);
      oacc[1][dg] = mfma16(vf1, pf[1][1], oacc[1][dg]);
    }

    __syncthreads();
  }

#pragma unroll
  for (int s = 0; s < 2; s++) {
    float inv = 1.0f / lrun[s];
    u16* orow = Og + (size_t)(b * TSEQ + qr + s * 64) * DMODEL + h * 64;
#pragma unroll
    for (int dg = 0; dg < 4; dg++) {
      ushort4 st = make_ushort4(f2b_hw(oacc[s][dg][0] * inv), f2b_hw(oacc[s][dg][1] * inv),
                                f2b_hw(oacc[s][dg][2] * inv), f2b_hw(oacc[s][dg][3] * inv));
      *(ushort4*)(orow + dg * 16 + lhi * 4) = st;
    }
  }
}

// ---------- launch ----------

extern "C" void kernel_launch(void* const* d_in, const int* in_sizes, int n_in,
                              void* d_out, int out_size, void* d_ws, size_t ws_size,
                              hipStream_t stream) {
  const float* x      = (const float*)d_in[0];
  const float* memory = (const float*)d_in[1];
  const float* sa_wq = (const float*)d_in[4];  const float* sa_bq = (const float*)d_in[5];
  const float* sa_wk = (const float*)d_in[6];  const float* sa_bk = (const float*)d_in[7];
  const float* sa_wv = (const float*)d_in[8];  const float* sa_bv = (const float*)d_in[9];
  const float* sa_wo = (const float*)d_in[10]; const float* sa_bo = (const float*)d_in[11];
  const float* ca_wq = (const float*)d_in[12]; const float* ca_bq = (const float*)d_in[13];
  const float* ca_wk = (const float*)d_in[14]; const float* ca_bk = (const float*)d_in[15];
  const float* ca_wv = (const float*)d_in[16]; const float* ca_bv = (const float*)d_in[17];
  const float* ca_wo = (const float*)d_in[18]; const float* ca_bo = (const float*)d_in[19];
  const float* ff_w1 = (const float*)d_in[20]; const float* ff_b1 = (const float*)d_in[21];
  const float* ff_w2 = (const float*)d_in[22]; const float* ff_b2 = (const float*)d_in[23];
  const float* ln1_w = (const float*)d_in[24]; const float* ln1_b = (const float*)d_in[25];
  const float* ln2_w = (const float*)d_in[26]; const float* ln2_b = (const float*)d_in[27];
  const float* ln3_w = (const float*)d_in[28]; const float* ln3_b = (const float*)d_in[29];
  float* out = (float*)d_out;

  char* ws = (char*)d_ws;
  const size_t MB = 1u << 20;
  u16* h_bf   = (u16*)(ws + 0 * MB);
  u16* mem_bf = (u16*)(ws + 8 * MB);
  u16* qb     = (u16*)(ws + 16 * MB);   // qb/kb/vb contiguous, 8MB apart
  u16* kb     = (u16*)(ws + 24 * MB);
  u16* vb     = (u16*)(ws + 32 * MB);   // holds V^T [bh][64][1024]
  u16* attnb  = (u16*)(ws + 40 * MB);
  u16* ffmid  = (u16*)(ws + 48 * MB);
  u16* w_sq   = (u16*)(ws + 80 * MB);   // w_sq/w_sk/w_sv contiguous
  u16* w_sk   = (u16*)(ws + 82 * MB);
  u16* w_sv   = (u16*)(ws + 84 * MB);
  u16* w_so   = (u16*)(ws + 86 * MB);
  u16* w_cq   = (u16*)(ws + 88 * MB);
  u16* w_ck   = (u16*)(ws + 90 * MB);   // w_ck/w_cv contiguous
  u16* w_cv   = (u16*)(ws + 92 * MB);
  u16* w_co   = (u16*)(ws + 94 * MB);
  u16* w_f1   = (u16*)(ws + 96 * MB);
  u16* w_f2   = (u16*)(ws + 104 * MB);

  F2B fa;
  fa.s[0] = sa_wq; fa.d[0] = w_sq;
  fa.s[1] = sa_wk; fa.d[1] = w_sk;
  fa.s[2] = sa_wv; fa.d[2] = w_sv;
  fa.s[3] = sa_wo; fa.d[3] = w_so;
  fa.s[4] = ca_wq; fa.d[4] = w_cq;
  fa.s[5] = ca_wk; fa.d[5] = w_ck;
  fa.s[6] = ca_wv; fa.d[6] = w_cv;
  fa.s[7] = ca_wo; fa.d[7] = w_co;
  fa.s[8] = ff_w1; fa.d[8] = w_f1;
  fa.s[9] = ff_w2; fa.d[9] = w_f2;
  fa.s[10] = memory; fa.d[10] = mem_bf;
  f2b_all<<<20480, 256, 0, stream>>>(fa);

  // ---- self-attention block ----
  ln_kernel<<<4096, 256, 0, stream>>>(x, ln1_w, ln1_b, h_bf);
  gemm_bt<2, false, false, 0, 2><<<768, 512, 0, stream>>>(
      h_bf, w_sq, sa_bq, sa_bk, sa_bv, nullptr, qb, NTOK, 3072, DMODEL, DMODEL, 24);
  attn_kernel<true><<<512, 256, 0, stream>>>(qb, kb, vb, attnb);
  gemm_bt<0, false><<<256, 512, 0, stream>>>(attnb, w_so, sa_bo, nullptr, nullptr,
                                             x, out, NTOK, DMODEL, DMODEL, DMODEL, 8);

  // ---- cross-attention block ----
  ln_kernel<<<4096, 256, 0, stream>>>(out, ln2_w, ln2_b, h_bf);
  gemm_bt<2, false, false, 0, -1><<<256, 512, 0, stream>>>(
      h_bf, w_cq, ca_bq, nullptr, nullptr, nullptr, qb, NTOK, DMODEL, DMODEL, DMODEL, 8);
  gemm_bt<2, false, false, -1, 1><<<512, 512, 0, stream>>>(
      mem_bf, w_ck, ca_bk, ca_bv, nullptr, nullptr, kb, NTOK, 2048, DMODEL, DMODEL, 16);
  attn_kernel<false><<<512, 256, 0, stream>>>(qb, kb, vb, attnb);
  gemm_bt<0, false><<<256, 512, 0, stream>>>(attnb, w_co, ca_bo, nullptr, nullptr,
                                             out, out, NTOK, DMODEL, DMODEL, DMODEL, 8);

  // ---- FFN block ----
  ln_kernel<<<4096, 256, 0, stream>>>(out, ln3_w, ln3_b, h_bf);
  gemm256<true><<<256, 512, 0, stream>>>(h_bf, w_f1, ff_b1, ffmid,
                                         NTOK, DFF, DMODEL, DMODEL, 16);
  gemm_bt<3, false, true><<<512, 512, 0, stream>>>(ffmid, w_f2, ff_b2, nullptr, nullptr,
                                                   nullptr, out, NTOK, DMODEL, 2048, DFF, 8);

  (void)in_sizes; (void)n_in; (void)out_size; (void)ws_size;
}

// Round 14
// 323.346 us; speedup vs baseline: 1.0312x; 1.0312x over previous
//
#include <hip/hip_runtime.h>
#include <hip/hip_bf16.h>

typedef unsigned short u16;
typedef __attribute__((ext_vector_type(4))) float f32x4;
typedef __attribute__((ext_vector_type(8))) short s16x8;
typedef __attribute__((ext_vector_type(4))) short s16x4;
typedef __attribute__((ext_vector_type(8))) __bf16 bf16x8;

#define NTOK 4096
#define DMODEL 1024
#define DFF 4096
#define NH 16
#define TSEQ 1024

#define SBAR() do { asm volatile("" ::: "memory"); __builtin_amdgcn_s_barrier(); asm volatile("" ::: "memory"); } while (0)

// ---------- helpers ----------

__device__ __forceinline__ u16 f2b_hw(float f) {
  union { __bf16 h; u16 u; } cv;
  cv.h = (__bf16)f;
  return cv.u;
}

__device__ __forceinline__ float b2f(u16 u) {
  return __uint_as_float(((unsigned)u) << 16);
}

__device__ __forceinline__ f32x4 mfma16(s16x8 a, s16x8 b, f32x4 c) {
  return __builtin_amdgcn_mfma_f32_16x16x32_bf16((bf16x8)a, (bf16x8)b, c, 0, 0, 0);
}

__device__ __forceinline__ void gload16(const u16* g, u16* l) {
  __builtin_amdgcn_global_load_lds(
      (const __attribute__((address_space(1))) unsigned int*)g,
      (__attribute__((address_space(3))) unsigned int*)l, 16, 0, 0);
}

// natural-layout fragment from a swizzled 64-elem-row LDS tile
__device__ __forceinline__ s16x8 ld8s(const u16* t, int row, int eoff) {
  int rx = row & 7;
  const u16* p1 = t + row * 64 + ((((eoff >> 3) ^ rx) << 3) | (eoff & 7));
  const u16* p2 = t + row * 64 + (((((eoff + 16) >> 3) ^ rx) << 3) | (eoff & 7));
  s16x4 lo = *(const s16x4*)p1;
  s16x4 hi = *(const s16x4*)p2;
  s16x8 r;
  r[0] = lo[0]; r[1] = lo[1]; r[2] = lo[2]; r[3] = lo[3];
  r[4] = hi[0]; r[5] = hi[1]; r[6] = hi[2]; r[7] = hi[3];
  return r;
}

// k-permuted (contiguous 16B, uniform permutation) fragment from swizzled tile
__device__ __forceinline__ s16x8 ld16s(const u16* t, int row, int ch) {
  return *(const s16x8*)(t + row * 64 + ((ch ^ (row & 7)) << 3));
}

// ---------- fused fp32 -> bf16 converts (11 segments, one kernel) ----------

struct F2B {
  const float* s[11];
  u16* d[11];
};

__global__ __launch_bounds__(256) void f2b_all(F2B a) {
  int bid = blockIdx.x;
  int seg, boff;
  if (bid < 8192) { seg = bid >> 10; boff = bid & 1023; }
  else { int j = bid - 8192; seg = 8 + (j >> 12); boff = j & 4095; }
  size_t i = ((size_t)boff * 256 + threadIdx.x) * 4;
  float4 v = *(const float4*)(a.s[seg] + i);
  ushort4 o = make_ushort4(f2b_hw(v.x), f2b_hw(v.y), f2b_hw(v.z), f2b_hw(v.w));
  *(ushort4*)(a.d[seg] + i) = o;
}

// ---------- LayerNorm ----------

__global__ __launch_bounds__(256) void ln_kernel(const float* __restrict__ x,
                                                 const float* __restrict__ w,
                                                 const float* __restrict__ b,
                                                 u16* __restrict__ out) {
  int row = blockIdx.x;
  int t = threadIdx.x;
  const float* xr = x + (size_t)row * DMODEL;
  float4 v = *(const float4*)(xr + t * 4);
  float s = v.x + v.y + v.z + v.w;
#pragma unroll
  for (int off = 1; off < 64; off <<= 1) s += __shfl_xor(s, off);
  __shared__ float red[8];
  int wid = t >> 6, lane = t & 63;
  if (lane == 0) red[wid] = s;
  __syncthreads();
  float mean = (red[0] + red[1] + red[2] + red[3]) * (1.0f / 1024.0f);
  float dx = v.x - mean, dy = v.y - mean, dz = v.z - mean, dw = v.w - mean;
  float ss = dx * dx + dy * dy + dz * dz + dw * dw;
#pragma unroll
  for (int off = 1; off < 64; off <<= 1) ss += __shfl_xor(ss, off);
  if (lane == 0) red[4 + wid] = ss;
  __syncthreads();
  float sst = red[4] + red[5] + red[6] + red[7];
  float inv = 1.0f / (sqrtf(sst / 1023.0f) + 1e-6f);
  float4 wv = *(const float4*)(w + t * 4);
  float4 bv = *(const float4*)(b + t * 4);
  ushort4 o = make_ushort4(f2b_hw(wv.x * dx * inv + bv.x), f2b_hw(wv.y * dy * inv + bv.y),
                           f2b_hw(wv.z * dz * inv + bv.z), f2b_hw(wv.w * dw * inv + bv.w));
  *(ushort4*)(out + (size_t)row * DMODEL + t * 4) = o;
}

// ---------- 256x256x64 8-phase GEMM (T2+T3+T4+T5), bf16 out (+RELU) ----------
// Round-12 proven: 0 bank conflicts, 45.0us on FF1 (vs 48.4 2-phase).

template <bool RELU>
__global__ __launch_bounds__(512, 2) void gemm256(const u16* __restrict__ A,
                                                  const u16* __restrict__ W,
                                                  const float* __restrict__ bias,
                                                  u16* __restrict__ out,
                                                  int M, int N, int K, int ld,
                                                  int gx) {
  __shared__ u16 As[2][2][8192];
  __shared__ u16 Bs[2][2][8192];
  const int nwg = gridDim.x, qch = nwg >> 3, bid = blockIdx.x;
  const int wg = (bid & 7) * qch + (bid >> 3);
  const int bx = wg % gx, by = wg / gx;
  const int m0 = by * 256, n0 = bx * 256;
  const int tid = threadIdx.x;
  const int wid = tid >> 6, lane = tid & 63;
  const int wr = wid >> 2, wc = wid & 3;
  const int lhi = lane >> 4, llo = lane & 15;
  f32x4 acc[8][4] = {};
  const int srow = tid >> 2;
  const int ssw = ((tid & 3) ^ ((srow >> 1) & 3)) << 3;  // pre-swizzled source chunk

  auto unitA = [&](int kt, int kh) {
    const u16* p = A + (size_t)(m0 + srow) * ld + kt * 64 + kh * 32 + ssw;
    gload16(p, &As[kt & 1][kh][tid * 8]);
    gload16(p + (size_t)128 * ld, &As[kt & 1][kh][4096 + tid * 8]);
  };
  auto unitB = [&](int kt, int kh) {
    const u16* p = W + (size_t)(n0 + srow) * ld + kt * 64 + kh * 32 + ssw;
    gload16(p, &Bs[kt & 1][kh][tid * 8]);
    gload16(p + (size_t)128 * ld, &Bs[kt & 1][kh][4096 + tid * 8]);
  };

  s16x8 bf[4];
  auto phase = [&](int d, int ch, int kh, bool loadB, auto stfn, int vm) {
    s16x8 af[4];
#pragma unroll
    for (int fm = 0; fm < 4; fm++) {
      int row = wr * 128 + ch * 64 + fm * 16 + llo;
      af[fm] = *(const s16x8*)(&As[d][kh][row * 32 + ((lhi ^ ((row >> 1) & 3)) << 3)]);
    }
    if (loadB) {
#pragma unroll
      for (int fn = 0; fn < 4; fn++) {
        int row = wc * 64 + fn * 16 + llo;
        bf[fn] = *(const s16x8*)(&Bs[d][kh][row * 32 + ((lhi ^ ((row >> 1) & 3)) << 3)]);
      }
    }
    stfn();
    SBAR();
    __builtin_amdgcn_s_setprio(1);
#pragma unroll
    for (int fm = 0; fm < 4; fm++)
#pragma unroll
      for (int fn = 0; fn < 4; fn++)
        acc[ch * 4 + fm][fn] = mfma16(af[fm], bf[fn], acc[ch * 4 + fm][fn]);
    __builtin_amdgcn_s_setprio(0);
    if (vm == 8) asm volatile("s_waitcnt vmcnt(8)" ::: "memory");
    else if (vm == 4) asm volatile("s_waitcnt vmcnt(4)" ::: "memory");
    else if (vm == 0) asm volatile("s_waitcnt vmcnt(0)" ::: "memory");
    SBAR();
  };

  // prologue: 6 units (t0 full + t1 k0)
  unitA(0, 0); unitB(0, 0); unitA(0, 1); unitB(0, 1); unitA(1, 0); unitB(1, 0);
  asm volatile("s_waitcnt vmcnt(8)" ::: "memory");
  SBAR();

  const int NPAIR = K >> 7;
#pragma unroll 1
  for (int i = 0; i < NPAIR; ++i) {
    const int tb = 2 * i + 1, tc = 2 * i + 2, td = 2 * i + 3;
    const bool nx = (i + 1 < NPAIR);
    phase(0, 0, 0, true,  [&] { unitA(tb, 1); }, -1);
    phase(0, 1, 0, false, [&] { unitB(tb, 1); }, 8);
    phase(0, 1, 1, true,  [&] { if (nx) unitA(tc, 0); }, -1);
    phase(0, 0, 1, false, [&] { if (nx) unitB(tc, 0); }, nx ? 8 : 4);
    phase(1, 0, 0, true,  [&] { if (nx) unitA(tc, 1); }, -1);
    phase(1, 1, 0, false, [&] { if (nx) unitB(tc, 1); }, nx ? 8 : 0);
    phase(1, 1, 1, true,  [&] { if (nx) unitA(td, 0); }, -1);
    phase(1, 0, 1, false, [&] { if (nx) unitB(td, 0); }, nx ? 8 : -1);
  }

#pragma unroll
  for (int ch = 0; ch < 2; ch++)
#pragma unroll
    for (int fm = 0; fm < 4; fm++)
#pragma unroll
      for (int fn = 0; fn < 4; fn++) {
        int r0 = m0 + wr * 128 + ch * 64 + fm * 16 + lhi * 4;
        int c = n0 + wc * 64 + fn * 16 + llo;
        float bv = bias[c];
#pragma unroll
        for (int i2 = 0; i2 < 4; i2++) {
          float v = acc[ch * 4 + fm][fn][i2] + bv;
          if (RELU) v = fmaxf(v, 0.0f);
          out[(size_t)(r0 + i2) * N + c] = f2b_hw(v);
        }
      }
  (void)M;
}

// ---------- 2-phase 512-thread GEMM (proven round-7/10 config) ----------
// MODE 0: fp32 out [M,N] (+resid); MODE 1: bf16 [M,N] (+RELU);
// MODE 2: packed heads (QBUF scaled, VBUF transposed);
// MODE 4 (SPLITK): bf16 partial at outp + half*M*N (no bias/resid).

template <int MODE, bool RELU, bool SPLITK = false, int QBUF = -1, int VBUF = -1>
__global__ __launch_bounds__(512) void gemm_bt(const u16* __restrict__ A,
                                               const u16* __restrict__ W,
                                               const float* __restrict__ b0,
                                               const float* __restrict__ b1,
                                               const float* __restrict__ b2,
                                               const float* resid, void* outp,
                                               int M, int N, int K, int ld,
                                               int gx) {
  __shared__ u16 As[2][128 * 64];
  __shared__ u16 Bs[2][128 * 64];
  const int nwg = gridDim.x;
  const int qch = nwg >> 3;
  const int bid = blockIdx.x;
  int wg = (bid & 7) * qch + (bid >> 3);
  int half = 0;
  if (SPLITK) { half = wg & 1; wg >>= 1; }
  const int bx = wg % gx, by = wg / gx;
  const int m0 = by * 128, n0 = bx * 128;
  if (SPLITK) { A += (size_t)half * K; W += (size_t)half * K; }
  const int tid = threadIdx.x;
  const int wid = tid >> 6, lane = tid & 63;
  const int wr = wid >> 2, wc = wid & 3;
  const int lhi = lane >> 4, llo = lane & 15;
  f32x4 acc[4][2] = {};
  const int sr = tid >> 3, sc = tid & 7;
  const int srcoff = (sc ^ (sr & 7)) << 3;

  auto stage = [&](int kk, int buf) {
    const u16* Ap = A + (size_t)(m0 + sr) * ld + kk + srcoff;
    gload16(Ap, &As[buf][tid * 8]);
    gload16(Ap + (size_t)64 * ld, &As[buf][4096 + tid * 8]);
    const u16* Wp = W + (size_t)(n0 + sr) * ld + kk + srcoff;
    gload16(Wp, &Bs[buf][tid * 8]);
    gload16(Wp + (size_t)64 * ld, &Bs[buf][4096 + tid * 8]);
  };

  stage(0, 0);
  __syncthreads();

  for (int k0 = 0; k0 < K; k0 += 64) {
    int cur = (k0 >> 6) & 1;
    if (k0 + 64 < K) stage(k0 + 64, cur ^ 1);
#pragma unroll
    for (int ks8 = 0; ks8 < 8; ks8 += 4) {
      s16x8 af[4], bfr[2];
#pragma unroll
      for (int f = 0; f < 4; f++) af[f] = ld16s(&As[cur][0], wr * 64 + f * 16 + llo, ks8 + lhi);
#pragma unroll
      for (int g = 0; g < 2; g++) bfr[g] = ld16s(&Bs[cur][0], wc * 32 + g * 16 + llo, ks8 + lhi);
#pragma unroll
      for (int f = 0; f < 4; f++)
#pragma unroll
        for (int g = 0; g < 2; g++) acc[f][g] = mfma16(af[f], bfr[g], acc[f][g]);
    }
    __syncthreads();
  }

#pragma unroll
  for (int fm = 0; fm < 4; fm++) {
#pragma unroll
    for (int fn = 0; fn < 2; fn++) {
      int c = n0 + wc * 32 + fn * 16 + llo;
      const int r0 = m0 + wr * 64 + fm * 16 + lhi * 4;
      if (MODE == 2) {
        int buf = c >> 10, cc = c & 1023;
        int hh = cc >> 6, d = cc & 63;
        int bb = r0 >> 10, t0 = r0 & 1023;
        const float* bias = (buf == 0) ? b0 : ((buf == 1) ? b1 : b2);
        float bv = bias[cc];
        float v4[4];
#pragma unroll
        for (int i = 0; i < 4; i++) {
          float v = acc[fm][fn][i] + bv;
          if (buf == QBUF) v *= 0.125f;
          v4[i] = v;
        }
        if (buf == VBUF) {
          ushort4 st = make_ushort4(f2b_hw(v4[0]), f2b_hw(v4[1]), f2b_hw(v4[2]), f2b_hw(v4[3]));
          *(ushort4*)(&((u16*)outp)[(size_t)buf * 4194304 +
                                    (((size_t)(bb * NH + hh)) * 64 + d) * TSEQ + t0]) = st;
        } else {
#pragma unroll
          for (int i = 0; i < 4; i++)
            ((u16*)outp)[(size_t)buf * 4194304 +
                         (((size_t)(bb * NH + hh)) * TSEQ + t0 + i) * 64 + d] = f2b_hw(v4[i]);
        }
      } else if (MODE == 4) {
#pragma unroll
        for (int i = 0; i < 4; i++)
          ((u16*)outp)[(size_t)half * M * N + (size_t)(r0 + i) * N + c] =
              f2b_hw(acc[fm][fn][i]);
      } else {
        float bv = b0 ? b0[c] : 0.0f;
#pragma unroll
        for (int i = 0; i < 4; i++) {
          int r = r0 + i;
          float v = acc[fm][fn][i] + bv;
          if (resid) v += resid[(size_t)r * N + c];
          if (RELU) v = fmaxf(v, 0.0f);
          if (MODE == 0) {
            ((float*)outp)[(size_t)r * N + c] = v;
          } else {
            ((u16*)outp)[(size_t)r * N + c] = f2b_hw(v);
          }
        }
      }
    }
  }
}

// ---------- split-K reduce (bf16 partials): out += p0 + p1 + bias ----------

__global__ __launch_bounds__(256) void ff2_reduce(const u16* __restrict__ p,
                                                  const float* __restrict__ bias,
                                                  float* __restrict__ out) {
  int row = blockIdx.x, t = threadIdx.x;
  size_t i = (size_t)row * 1024 + t * 4;
  const u16* p1 = p + (size_t)4194304;
  s16x4 a = *(const s16x4*)(p + i);
  s16x4 b = *(const s16x4*)(p1 + i);
  float4 r = *(const float4*)(out + i);
  float4 bv = *(const float4*)(bias + t * 4);
  float4 o = make_float4(b2f((u16)a[0]) + b2f((u16)b[0]) + r.x + bv.x,
                         b2f((u16)a[1]) + b2f((u16)b[1]) + r.y + bv.y,
                         b2f((u16)a[2]) + b2f((u16)b[2]) + r.z + bv.z,
                         b2f((u16)a[3]) + b2f((u16)b[3]) + r.w + bv.w);
  *(float4*)(out + i) = o;
}

// ---------- flash attention (round-10 proven, causal-balanced) ----------

template <bool CAUSAL>
__global__ __launch_bounds__(256) void attn_kernel(const u16* __restrict__ Qg,
                                                   const u16* __restrict__ Kg,
                                                   const u16* __restrict__ Vt,
                                                   u16* __restrict__ Og) {
  const int bid = blockIdx.x;
  const int wg = (bid & 7) * 64 + (bid >> 3);
  const int bh = wg >> 3;
  const int qblk = (wg & 7) ^ (CAUSAL ? 7 * ((bid >> 8) & 1) : 0);
  const int b = bh >> 4, h = bh & 15;
  const int q0 = qblk * 128;
  const int tid = threadIdx.x, wid = tid >> 6, lane = tid & 63;
  const int lhi = lane >> 4, llo = lane & 15;
  __shared__ u16 Ks[2][4096];
  __shared__ u16 Vs[2][4096];

  const int qr = q0 + wid * 16 + llo;
  const u16* qp0 = Qg + ((size_t)bh * TSEQ + qr) * 64;
  s16x8 qf[2][2];
  qf[0][0] = *(const s16x8*)(qp0 + 8 * lhi);
  qf[0][1] = *(const s16x8*)(qp0 + 8 * (4 + lhi));
  qf[1][0] = *(const s16x8*)(qp0 + 4096 + 8 * lhi);
  qf[1][1] = *(const s16x8*)(qp0 + 4096 + 8 * (4 + lhi));

  f32x4 oacc[2][4] = {};
  float mrun[2] = {-1.0e30f, -1.0e30f}, lrun[2] = {0.0f, 0.0f};
  const size_t kvb = (size_t)bh * (TSEQ * 64);
  const int nt = CAUSAL ? ((q0 + 128) >> 6) : (TSEQ >> 6);

  const int srow = tid >> 3;
  const int ssw = ((tid & 7) ^ (srow & 7)) << 3;

  auto stageK = [&](int s0, int buf) {
    const u16* kb = Kg + kvb + (size_t)s0 * 64;
    gload16(kb + (size_t)srow * 64 + ssw, &Ks[buf][tid * 8]);
    gload16(kb + (size_t)(32 + srow) * 64 + ssw, &Ks[buf][2048 + tid * 8]);
  };
  auto stageV = [&](int s0, int buf) {
    const u16* vb2 = Vt + kvb + s0;
    gload16(vb2 + (size_t)srow * TSEQ + ssw, &Vs[buf][tid * 8]);
    gload16(vb2 + (size_t)(32 + srow) * TSEQ + ssw, &Vs[buf][2048 + tid * 8]);
  };

  stageK(0, 0);
  stageV(0, 0);
  __syncthreads();

  for (int t = 0; t < nt; ++t) {
    int cur = t & 1;
    if (t + 1 < nt) {
      stageK((t + 1) * 64, cur ^ 1);
      stageV((t + 1) * 64, cur ^ 1);
    }
    int s0 = t * 64;
    const bool act0 = !CAUSAL || (s0 < q0 + 64);

    s16x8 kf[4][2];
#pragma unroll
    for (int g = 0; g < 4; g++) {
      kf[g][0] = ld16s(&Ks[cur][0], g * 16 + llo, lhi);
      kf[g][1] = ld16s(&Ks[cur][0], g * 16 + llo, 4 + lhi);
    }

    s16x8 pf[2][2];
#pragma unroll
    for (int s = 0; s < 2; s++) {
      if (s == 0 && !act0) continue;
      f32x4 sacc[4] = {};
#pragma unroll
      for (int g = 0; g < 4; g++) {
        sacc[g] = mfma16(kf[g][0], qf[s][0], sacc[g]);
        sacc[g] = mfma16(kf[g][1], qf[s][1], sacc[g]);
      }
      const int qrow = qr + s * 64;
      const bool diag = CAUSAL && (s0 == q0 + s * 64);
      float sv[16];
      float pmax = -1.0e30f;
#pragma unroll
      for (int g = 0; g < 4; g++)
#pragma unroll
        for (int i = 0; i < 4; i++) {
          float sc = sacc[g][i];
          if (diag) {
            int kv = s0 + g * 16 + lhi * 4 + i;
            if (kv > qrow) sc = -1.0e9f;
          }
          sv[g * 4 + i] = sc;
          pmax = fmaxf(pmax, sc);
        }
      pmax = fmaxf(pmax, __shfl_xor(pmax, 16));
      pmax = fmaxf(pmax, __shfl_xor(pmax, 32));
      if (!__all(pmax - mrun[s] <= 8.0f)) {
        float mnew = fmaxf(mrun[s], pmax);
        float alpha = __expf(mrun[s] - mnew);
        lrun[s] *= alpha;
#pragma unroll
        for (int g = 0; g < 4; g++) {
          oacc[s][g][0] *= alpha; oacc[s][g][1] *= alpha;
          oacc[s][g][2] *= alpha; oacc[s][g][3] *= alpha;
        }
        mrun[s] = mnew;
      }
      float ls = 0.0f;
#pragma unroll
      for (int j = 0; j < 16; j++) {
        float p = __expf(sv[j] - mrun[s]);
        ls += p;
        pf[s][j >> 3][((j >> 2) & 1) * 4 + (j & 3)] = (short)f2b_hw(p);
      }
      ls += __shfl_xor(ls, 16);
      ls += __shfl_xor(ls, 32);
      lrun[s] += ls;
    }

#pragma unroll
    for (int dg = 0; dg < 4; dg++) {
      int row = dg * 16 + llo;
      s16x8 vf0 = ld8s(&Vs[cur][0], row, lhi * 4);
      s16x8 vf1 = ld8s(&Vs[cur][0], row, 32 + lhi * 4);
      if (act0) {
        oacc[0][dg] = mfma16(vf0, pf[0][0], oacc[0][dg]);
        oacc[0][dg] = mfma16(vf1, pf[0][1], oacc[0][dg]);
      }
      oacc[1][dg] = mfma16(vf0, pf[1][0], oacc[1][dg]);
      oacc[1][dg] = mfma16(vf1, pf[1][1], oacc[1][dg]);
    }

    __syncthreads();
  }

#pragma unroll
  for (int s = 0; s < 2; s++) {
    float inv = 1.0f / lrun[s];
    u16* orow = Og + (size_t)(b * TSEQ + qr + s * 64) * DMODEL + h * 64;
#pragma unroll
    for (int dg = 0; dg < 4; dg++) {
      ushort4 st = make_ushort4(f2b_hw(oacc[s][dg][0] * inv), f2b_hw(oacc[s][dg][1] * inv),
                                f2b_hw(oacc[s][dg][2] * inv), f2b_hw(oacc[s][dg][3] * inv));
      *(ushort4*)(orow + dg * 16 + lhi * 4) = st;
    }
  }
}

// ---------- launch ----------

extern "C" void kernel_launch(void* const* d_in, const int* in_sizes, int n_in,
                              void* d_out, int out_size, void* d_ws, size_t ws_size,
                              hipStream_t stream) {
  const float* x      = (const float*)d_in[0];
  const float* memory = (const float*)d_in[1];
  const float* sa_wq = (const float*)d_in[4];  const float* sa_bq = (const float*)d_in[5];
  const float* sa_wk = (const float*)d_in[6];  const float* sa_bk = (const float*)d_in[7];
  const float* sa_wv = (const float*)d_in[8];  const float* sa_bv = (const float*)d_in[9];
  const float* sa_wo = (const float*)d_in[10]; const float* sa_bo = (const float*)d_in[11];
  const float* ca_wq = (const float*)d_in[12]; const float* ca_bq = (const float*)d_in[13];
  const float* ca_wk = (const float*)d_in[14]; const float* ca_bk = (const float*)d_in[15];
  const float* ca_wv = (const float*)d_in[16]; const float* ca_bv = (const float*)d_in[17];
  const float* ca_wo = (const float*)d_in[18]; const float* ca_bo = (const float*)d_in[19];
  const float* ff_w1 = (const float*)d_in[20]; const float* ff_b1 = (const float*)d_in[21];
  const float* ff_w2 = (const float*)d_in[22]; const float* ff_b2 = (const float*)d_in[23];
  const float* ln1_w = (const float*)d_in[24]; const float* ln1_b = (const float*)d_in[25];
  const float* ln2_w = (const float*)d_in[26]; const float* ln2_b = (const float*)d_in[27];
  const float* ln3_w = (const float*)d_in[28]; const float* ln3_b = (const float*)d_in[29];
  float* out = (float*)d_out;

  char* ws = (char*)d_ws;
  const size_t MB = 1u << 20;
  u16* h_bf   = (u16*)(ws + 0 * MB);
  u16* mem_bf = (u16*)(ws + 8 * MB);
  u16* qb     = (u16*)(ws + 16 * MB);   // qb/kb/vb contiguous, 8MB apart
  u16* kb     = (u16*)(ws + 24 * MB);
  u16* vb     = (u16*)(ws + 32 * MB);   // holds V^T [bh][64][1024]
  u16* attnb  = (u16*)(ws + 40 * MB);
  u16* ffmid  = (u16*)(ws + 48 * MB);
  u16* pk     = (u16*)(ws + 16 * MB);   // split-K bf16 partials (reuse qb/kb, 16MB)
  u16* w_sq   = (u16*)(ws + 80 * MB);   // w_sq/w_sk/w_sv contiguous
  u16* w_sk   = (u16*)(ws + 82 * MB);
  u16* w_sv   = (u16*)(ws + 84 * MB);
  u16* w_so   = (u16*)(ws + 86 * MB);
  u16* w_cq   = (u16*)(ws + 88 * MB);
  u16* w_ck   = (u16*)(ws + 90 * MB);   // w_ck/w_cv contiguous
  u16* w_cv   = (u16*)(ws + 92 * MB);
  u16* w_co   = (u16*)(ws + 94 * MB);
  u16* w_f1   = (u16*)(ws + 96 * MB);
  u16* w_f2   = (u16*)(ws + 104 * MB);

  F2B fa;
  fa.s[0] = sa_wq; fa.d[0] = w_sq;
  fa.s[1] = sa_wk; fa.d[1] = w_sk;
  fa.s[2] = sa_wv; fa.d[2] = w_sv;
  fa.s[3] = sa_wo; fa.d[3] = w_so;
  fa.s[4] = ca_wq; fa.d[4] = w_cq;
  fa.s[5] = ca_wk; fa.d[5] = w_ck;
  fa.s[6] = ca_wv; fa.d[6] = w_cv;
  fa.s[7] = ca_wo; fa.d[7] = w_co;
  fa.s[8] = ff_w1; fa.d[8] = w_f1;
  fa.s[9] = ff_w2; fa.d[9] = w_f2;
  fa.s[10] = memory; fa.d[10] = mem_bf;
  f2b_all<<<20480, 256, 0, stream>>>(fa);

  // ---- self-attention block ----
  ln_kernel<<<4096, 256, 0, stream>>>(x, ln1_w, ln1_b, h_bf);
  gemm_bt<2, false, false, 0, 2><<<768, 512, 0, stream>>>(
      h_bf, w_sq, sa_bq, sa_bk, sa_bv, nullptr, qb, NTOK, 3072, DMODEL, DMODEL, 24);
  attn_kernel<true><<<512, 256, 0, stream>>>(qb, kb, vb, attnb);
  gemm_bt<0, false><<<256, 512, 0, stream>>>(attnb, w_so, sa_bo, nullptr, nullptr,
                                             x, out, NTOK, DMODEL, DMODEL, DMODEL, 8);

  // ---- cross-attention block ----
  ln_kernel<<<4096, 256, 0, stream>>>(out, ln2_w, ln2_b, h_bf);
  gemm_bt<2, false, false, 0, -1><<<256, 512, 0, stream>>>(
      h_bf, w_cq, ca_bq, nullptr, nullptr, nullptr, qb, NTOK, DMODEL, DMODEL, DMODEL, 8);
  gemm_bt<2, false, false, -1, 1><<<512, 512, 0, stream>>>(
      mem_bf, w_ck, ca_bk, ca_bv, nullptr, nullptr, kb, NTOK, 2048, DMODEL, DMODEL, 16);
  attn_kernel<false><<<512, 256, 0, stream>>>(qb, kb, vb, attnb);
  gemm_bt<0, false><<<256, 512, 0, stream>>>(attnb, w_co, ca_bo, nullptr, nullptr,
                                             out, out, NTOK, DMODEL, DMODEL, DMODEL, 8);

  // ---- FFN block ----
  ln_kernel<<<4096, 256, 0, stream>>>(out, ln3_w, ln3_b, h_bf);
  gemm256<true><<<256, 512, 0, stream>>>(h_bf, w_f1, ff_b1, ffmid,
                                         NTOK, DFF, DMODEL, DMODEL, 16);
  gemm_bt<4, false, true><<<512, 512, 0, stream>>>(ffmid, w_f2, nullptr, nullptr, nullptr,
                                                   nullptr, pk, NTOK, DMODEL, 2048, DFF, 8);
  ff2_reduce<<<4096, 256, 0, stream>>>(pk, ff_b2, out);

  (void)in_sizes; (void)n_in; (void)out_size; (void)ws_size;
}

// Round 15
// 320.764 us; speedup vs baseline: 1.0395x; 1.0080x over previous
//
#include <hip/hip_runtime.h>
#include <hip/hip_bf16.h>

typedef unsigned short u16;
typedef __attribute__((ext_vector_type(4))) float f32x4;
typedef __attribute__((ext_vector_type(8))) short s16x8;
typedef __attribute__((ext_vector_type(4))) short s16x4;
typedef __attribute__((ext_vector_type(8))) __bf16 bf16x8;

#define NTOK 4096
#define DMODEL 1024
#define DFF 4096
#define NH 16
#define TSEQ 1024

#define SBAR() do { asm volatile("" ::: "memory"); __builtin_amdgcn_s_barrier(); asm volatile("" ::: "memory"); } while (0)

// ---------- helpers ----------

__device__ __forceinline__ u16 f2b_hw(float f) {
  union { __bf16 h; u16 u; } cv;
  cv.h = (__bf16)f;
  return cv.u;
}

__device__ __forceinline__ float b2f(u16 u) {
  return __uint_as_float(((unsigned)u) << 16);
}

__device__ __forceinline__ f32x4 mfma16(s16x8 a, s16x8 b, f32x4 c) {
  return __builtin_amdgcn_mfma_f32_16x16x32_bf16((bf16x8)a, (bf16x8)b, c, 0, 0, 0);
}

__device__ __forceinline__ void gload16(const u16* g, u16* l) {
  __builtin_amdgcn_global_load_lds(
      (const __attribute__((address_space(1))) unsigned int*)g,
      (__attribute__((address_space(3))) unsigned int*)l, 16, 0, 0);
}

// natural-layout fragment from a swizzled 64-elem-row LDS tile
__device__ __forceinline__ s16x8 ld8s(const u16* t, int row, int eoff) {
  int rx = row & 7;
  const u16* p1 = t + row * 64 + ((((eoff >> 3) ^ rx) << 3) | (eoff & 7));
  const u16* p2 = t + row * 64 + (((((eoff + 16) >> 3) ^ rx) << 3) | (eoff & 7));
  s16x4 lo = *(const s16x4*)p1;
  s16x4 hi = *(const s16x4*)p2;
  s16x8 r;
  r[0] = lo[0]; r[1] = lo[1]; r[2] = lo[2]; r[3] = lo[3];
  r[4] = hi[0]; r[5] = hi[1]; r[6] = hi[2]; r[7] = hi[3];
  return r;
}

// k-permuted (contiguous 16B, uniform permutation) fragment from swizzled tile
__device__ __forceinline__ s16x8 ld16s(const u16* t, int row, int ch) {
  return *(const s16x8*)(t + row * 64 + ((ch ^ (row & 7)) << 3));
}

// ---------- fused fp32 -> bf16 converts (11 segments, one kernel) ----------

struct F2B {
  const float* s[11];
  u16* d[11];
};

__global__ __launch_bounds__(256) void f2b_all(F2B a) {
  int bid = blockIdx.x;
  int seg, boff;
  if (bid < 8192) { seg = bid >> 10; boff = bid & 1023; }
  else { int j = bid - 8192; seg = 8 + (j >> 12); boff = j & 4095; }
  size_t i = ((size_t)boff * 256 + threadIdx.x) * 4;
  float4 v = *(const float4*)(a.s[seg] + i);
  ushort4 o = make_ushort4(f2b_hw(v.x), f2b_hw(v.y), f2b_hw(v.z), f2b_hw(v.w));
  *(ushort4*)(a.d[seg] + i) = o;
}

// ---------- LayerNorm ----------

__global__ __launch_bounds__(256) void ln_kernel(const float* __restrict__ x,
                                                 const float* __restrict__ w,
                                                 const float* __restrict__ b,
                                                 u16* __restrict__ out) {
  int row = blockIdx.x;
  int t = threadIdx.x;
  const float* xr = x + (size_t)row * DMODEL;
  float4 v = *(const float4*)(xr + t * 4);
  float s = v.x + v.y + v.z + v.w;
#pragma unroll
  for (int off = 1; off < 64; off <<= 1) s += __shfl_xor(s, off);
  __shared__ float red[8];
  int wid = t >> 6, lane = t & 63;
  if (lane == 0) red[wid] = s;
  __syncthreads();
  float mean = (red[0] + red[1] + red[2] + red[3]) * (1.0f / 1024.0f);
  float dx = v.x - mean, dy = v.y - mean, dz = v.z - mean, dw = v.w - mean;
  float ss = dx * dx + dy * dy + dz * dz + dw * dw;
#pragma unroll
  for (int off = 1; off < 64; off <<= 1) ss += __shfl_xor(ss, off);
  if (lane == 0) red[4 + wid] = ss;
  __syncthreads();
  float sst = red[4] + red[5] + red[6] + red[7];
  float inv = 1.0f / (sqrtf(sst / 1023.0f) + 1e-6f);
  float4 wv = *(const float4*)(w + t * 4);
  float4 bv = *(const float4*)(b + t * 4);
  ushort4 o = make_ushort4(f2b_hw(wv.x * dx * inv + bv.x), f2b_hw(wv.y * dy * inv + bv.y),
                           f2b_hw(wv.z * dz * inv + bv.z), f2b_hw(wv.w * dw * inv + bv.w));
  *(ushort4*)(out + (size_t)row * DMODEL + t * 4) = o;
}

// ---------- 256x256x64 8-phase GEMM (T2+T3+T4+T5), bf16 out (+RELU) ----------
// Round-12 proven: 0 bank conflicts, 45.0us on FF1 (vs 48.4 2-phase).

template <bool RELU>
__global__ __launch_bounds__(512, 2) void gemm256(const u16* __restrict__ A,
                                                  const u16* __restrict__ W,
                                                  const float* __restrict__ bias,
                                                  u16* __restrict__ out,
                                                  int M, int N, int K, int ld,
                                                  int gx) {
  __shared__ u16 As[2][2][8192];
  __shared__ u16 Bs[2][2][8192];
  const int nwg = gridDim.x, qch = nwg >> 3, bid = blockIdx.x;
  const int wg = (bid & 7) * qch + (bid >> 3);
  const int bx = wg % gx, by = wg / gx;
  const int m0 = by * 256, n0 = bx * 256;
  const int tid = threadIdx.x;
  const int wid = tid >> 6, lane = tid & 63;
  const int wr = wid >> 2, wc = wid & 3;
  const int lhi = lane >> 4, llo = lane & 15;
  f32x4 acc[8][4] = {};
  const int srow = tid >> 2;
  const int ssw = ((tid & 3) ^ ((srow >> 1) & 3)) << 3;  // pre-swizzled source chunk

  auto unitA = [&](int kt, int kh) {
    const u16* p = A + (size_t)(m0 + srow) * ld + kt * 64 + kh * 32 + ssw;
    gload16(p, &As[kt & 1][kh][tid * 8]);
    gload16(p + (size_t)128 * ld, &As[kt & 1][kh][4096 + tid * 8]);
  };
  auto unitB = [&](int kt, int kh) {
    const u16* p = W + (size_t)(n0 + srow) * ld + kt * 64 + kh * 32 + ssw;
    gload16(p, &Bs[kt & 1][kh][tid * 8]);
    gload16(p + (size_t)128 * ld, &Bs[kt & 1][kh][4096 + tid * 8]);
  };

  s16x8 bf[4];
  auto phase = [&](int d, int ch, int kh, bool loadB, auto stfn, int vm) {
    s16x8 af[4];
#pragma unroll
    for (int fm = 0; fm < 4; fm++) {
      int row = wr * 128 + ch * 64 + fm * 16 + llo;
      af[fm] = *(const s16x8*)(&As[d][kh][row * 32 + ((lhi ^ ((row >> 1) & 3)) << 3)]);
    }
    if (loadB) {
#pragma unroll
      for (int fn = 0; fn < 4; fn++) {
        int row = wc * 64 + fn * 16 + llo;
        bf[fn] = *(const s16x8*)(&Bs[d][kh][row * 32 + ((lhi ^ ((row >> 1) & 3)) << 3)]);
      }
    }
    stfn();
    SBAR();
    __builtin_amdgcn_s_setprio(1);
#pragma unroll
    for (int fm = 0; fm < 4; fm++)
#pragma unroll
      for (int fn = 0; fn < 4; fn++)
        acc[ch * 4 + fm][fn] = mfma16(af[fm], bf[fn], acc[ch * 4 + fm][fn]);
    __builtin_amdgcn_s_setprio(0);
    if (vm == 8) asm volatile("s_waitcnt vmcnt(8)" ::: "memory");
    else if (vm == 4) asm volatile("s_waitcnt vmcnt(4)" ::: "memory");
    else if (vm == 0) asm volatile("s_waitcnt vmcnt(0)" ::: "memory");
    SBAR();
  };

  // prologue: 6 units (t0 full + t1 k0)
  unitA(0, 0); unitB(0, 0); unitA(0, 1); unitB(0, 1); unitA(1, 0); unitB(1, 0);
  asm volatile("s_waitcnt vmcnt(8)" ::: "memory");
  SBAR();

  const int NPAIR = K >> 7;
#pragma unroll 1
  for (int i = 0; i < NPAIR; ++i) {
    const int tb = 2 * i + 1, tc = 2 * i + 2, td = 2 * i + 3;
    const bool nx = (i + 1 < NPAIR);
    phase(0, 0, 0, true,  [&] { unitA(tb, 1); }, -1);
    phase(0, 1, 0, false, [&] { unitB(tb, 1); }, 8);
    phase(0, 1, 1, true,  [&] { if (nx) unitA(tc, 0); }, -1);
    phase(0, 0, 1, false, [&] { if (nx) unitB(tc, 0); }, nx ? 8 : 4);
    phase(1, 0, 0, true,  [&] { if (nx) unitA(tc, 1); }, -1);
    phase(1, 1, 0, false, [&] { if (nx) unitB(tc, 1); }, nx ? 8 : 0);
    phase(1, 1, 1, true,  [&] { if (nx) unitA(td, 0); }, -1);
    phase(1, 0, 1, false, [&] { if (nx) unitB(td, 0); }, nx ? 8 : -1);
  }

#pragma unroll
  for (int ch = 0; ch < 2; ch++)
#pragma unroll
    for (int fm = 0; fm < 4; fm++)
#pragma unroll
      for (int fn = 0; fn < 4; fn++) {
        int r0 = m0 + wr * 128 + ch * 64 + fm * 16 + lhi * 4;
        int c = n0 + wc * 64 + fn * 16 + llo;
        float bv = bias[c];
#pragma unroll
        for (int i2 = 0; i2 < 4; i2++) {
          float v = acc[ch * 4 + fm][fn][i2] + bv;
          if (RELU) v = fmaxf(v, 0.0f);
          out[(size_t)(r0 + i2) * N + c] = f2b_hw(v);
        }
      }
  (void)M;
}

// ---------- 2-phase 512-thread GEMM (proven round-7/10 config) ----------
// MODE 0: fp32 out [M,N] (+resid); MODE 1: bf16 [M,N] (+RELU);
// MODE 2: packed heads (QBUF scaled, VBUF transposed); A2 (optional):
//   block-uniform alternate A for output segments n0 >= 1024 (cross q+kv merge).
// MODE 4 (SPLITK): bf16 partial at outp + half*M*N (no bias/resid).

template <int MODE, bool RELU, bool SPLITK = false, int QBUF = -1, int VBUF = -1>
__global__ __launch_bounds__(512) void gemm_bt(const u16* __restrict__ A,
                                               const u16* __restrict__ A2,
                                               const u16* __restrict__ W,
                                               const float* __restrict__ b0,
                                               const float* __restrict__ b1,
                                               const float* __restrict__ b2,
                                               const float* resid, void* outp,
                                               int M, int N, int K, int ld,
                                               int gx) {
  __shared__ u16 As[2][128 * 64];
  __shared__ u16 Bs[2][128 * 64];
  const int nwg = gridDim.x;
  const int qch = nwg >> 3;
  const int bid = blockIdx.x;
  int wg = (bid & 7) * qch + (bid >> 3);
  int half = 0;
  if (SPLITK) { half = wg & 1; wg >>= 1; }
  const int bx = wg % gx, by = wg / gx;
  const int m0 = by * 128, n0 = bx * 128;
  if (SPLITK) { A += (size_t)half * K; W += (size_t)half * K; }
  if (MODE == 2 && A2 != nullptr && n0 >= 1024) A = A2;  // block-uniform select
  const int tid = threadIdx.x;
  const int wid = tid >> 6, lane = tid & 63;
  const int wr = wid >> 2, wc = wid & 3;
  const int lhi = lane >> 4, llo = lane & 15;
  f32x4 acc[4][2] = {};
  const int sr = tid >> 3, sc = tid & 7;
  const int srcoff = (sc ^ (sr & 7)) << 3;

  auto stage = [&](int kk, int buf) {
    const u16* Ap = A + (size_t)(m0 + sr) * ld + kk + srcoff;
    gload16(Ap, &As[buf][tid * 8]);
    gload16(Ap + (size_t)64 * ld, &As[buf][4096 + tid * 8]);
    const u16* Wp = W + (size_t)(n0 + sr) * ld + kk + srcoff;
    gload16(Wp, &Bs[buf][tid * 8]);
    gload16(Wp + (size_t)64 * ld, &Bs[buf][4096 + tid * 8]);
  };

  stage(0, 0);
  __syncthreads();

  for (int k0 = 0; k0 < K; k0 += 64) {
    int cur = (k0 >> 6) & 1;
    if (k0 + 64 < K) stage(k0 + 64, cur ^ 1);
#pragma unroll
    for (int ks8 = 0; ks8 < 8; ks8 += 4) {
      s16x8 af[4], bfr[2];
#pragma unroll
      for (int f = 0; f < 4; f++) af[f] = ld16s(&As[cur][0], wr * 64 + f * 16 + llo, ks8 + lhi);
#pragma unroll
      for (int g = 0; g < 2; g++) bfr[g] = ld16s(&Bs[cur][0], wc * 32 + g * 16 + llo, ks8 + lhi);
#pragma unroll
      for (int f = 0; f < 4; f++)
#pragma unroll
        for (int g = 0; g < 2; g++) acc[f][g] = mfma16(af[f], bfr[g], acc[f][g]);
    }
    __syncthreads();
  }

#pragma unroll
  for (int fm = 0; fm < 4; fm++) {
#pragma unroll
    for (int fn = 0; fn < 2; fn++) {
      int c = n0 + wc * 32 + fn * 16 + llo;
      const int r0 = m0 + wr * 64 + fm * 16 + lhi * 4;
      if (MODE == 2) {
        int buf = c >> 10, cc = c & 1023;
        int hh = cc >> 6, d = cc & 63;
        int bb = r0 >> 10, t0 = r0 & 1023;
        const float* bias = (buf == 0) ? b0 : ((buf == 1) ? b1 : b2);
        float bv = bias[cc];
        float v4[4];
#pragma unroll
        for (int i = 0; i < 4; i++) {
          float v = acc[fm][fn][i] + bv;
          if (buf == QBUF) v *= 0.125f;
          v4[i] = v;
        }
        if (buf == VBUF) {
          ushort4 st = make_ushort4(f2b_hw(v4[0]), f2b_hw(v4[1]), f2b_hw(v4[2]), f2b_hw(v4[3]));
          *(ushort4*)(&((u16*)outp)[(size_t)buf * 4194304 +
                                    (((size_t)(bb * NH + hh)) * 64 + d) * TSEQ + t0]) = st;
        } else {
#pragma unroll
          for (int i = 0; i < 4; i++)
            ((u16*)outp)[(size_t)buf * 4194304 +
                         (((size_t)(bb * NH + hh)) * TSEQ + t0 + i) * 64 + d] = f2b_hw(v4[i]);
        }
      } else if (MODE == 4) {
#pragma unroll
        for (int i = 0; i < 4; i++)
          ((u16*)outp)[(size_t)half * M * N + (size_t)(r0 + i) * N + c] =
              f2b_hw(acc[fm][fn][i]);
      } else {
        float bv = b0 ? b0[c] : 0.0f;
#pragma unroll
        for (int i = 0; i < 4; i++) {
          int r = r0 + i;
          float v = acc[fm][fn][i] + bv;
          if (resid) v += resid[(size_t)r * N + c];
          if (RELU) v = fmaxf(v, 0.0f);
          if (MODE == 0) {
            ((float*)outp)[(size_t)r * N + c] = v;
          } else {
            ((u16*)outp)[(size_t)r * N + c] = f2b_hw(v);
          }
        }
      }
    }
  }
}

// ---------- split-K reduce (bf16 partials): out += p0 + p1 + bias ----------

__global__ __launch_bounds__(256) void ff2_reduce(const u16* __restrict__ p,
                                                  const float* __restrict__ bias,
                                                  float* __restrict__ out) {
  int row = blockIdx.x, t = threadIdx.x;
  size_t i = (size_t)row * 1024 + t * 4;
  const u16* p1 = p + (size_t)4194304;
  s16x4 a = *(const s16x4*)(p + i);
  s16x4 b = *(const s16x4*)(p1 + i);
  float4 r = *(const float4*)(out + i);
  float4 bv = *(const float4*)(bias + t * 4);
  float4 o = make_float4(b2f((u16)a[0]) + b2f((u16)b[0]) + r.x + bv.x,
                         b2f((u16)a[1]) + b2f((u16)b[1]) + r.y + bv.y,
                         b2f((u16)a[2]) + b2f((u16)b[2]) + r.z + bv.z,
                         b2f((u16)a[3]) + b2f((u16)b[3]) + r.w + bv.w);
  *(float4*)(out + i) = o;
}

// ---------- flash attention (round-10 proven, causal-balanced) ----------

template <bool CAUSAL>
__global__ __launch_bounds__(256) void attn_kernel(const u16* __restrict__ Qg,
                                                   const u16* __restrict__ Kg,
                                                   const u16* __restrict__ Vt,
                                                   u16* __restrict__ Og) {
  const int bid = blockIdx.x;
  const int wg = (bid & 7) * 64 + (bid >> 3);
  const int bh = wg >> 3;
  const int qblk = (wg & 7) ^ (CAUSAL ? 7 * ((bid >> 8) & 1) : 0);
  const int b = bh >> 4, h = bh & 15;
  const int q0 = qblk * 128;
  const int tid = threadIdx.x, wid = tid >> 6, lane = tid & 63;
  const int lhi = lane >> 4, llo = lane & 15;
  __shared__ u16 Ks[2][4096];
  __shared__ u16 Vs[2][4096];

  const int qr = q0 + wid * 16 + llo;
  const u16* qp0 = Qg + ((size_t)bh * TSEQ + qr) * 64;
  s16x8 qf[2][2];
  qf[0][0] = *(const s16x8*)(qp0 + 8 * lhi);
  qf[0][1] = *(const s16x8*)(qp0 + 8 * (4 + lhi));
  qf[1][0] = *(const s16x8*)(qp0 + 4096 + 8 * lhi);
  qf[1][1] = *(const s16x8*)(qp0 + 4096 + 8 * (4 + lhi));

  f32x4 oacc[2][4] = {};
  float mrun[2] = {-1.0e30f, -1.0e30f}, lrun[2] = {0.0f, 0.0f};
  const size_t kvb = (size_t)bh * (TSEQ * 64);
  const int nt = CAUSAL ? ((q0 + 128) >> 6) : (TSEQ >> 6);

  const int srow = tid >> 3;
  const int ssw = ((tid & 7) ^ (srow & 7)) << 3;

  auto stageK = [&](int s0, int buf) {
    const u16* kb = Kg + kvb + (size_t)s0 * 64;
    gload16(kb + (size_t)srow * 64 + ssw, &Ks[buf][tid * 8]);
    gload16(kb + (size_t)(32 + srow) * 64 + ssw, &Ks[buf][2048 + tid * 8]);
  };
  auto stageV = [&](int s0, int buf) {
    const u16* vb2 = Vt + kvb + s0;
    gload16(vb2 + (size_t)srow * TSEQ + ssw, &Vs[buf][tid * 8]);
    gload16(vb2 + (size_t)(32 + srow) * TSEQ + ssw, &Vs[buf][2048 + tid * 8]);
  };

  stageK(0, 0);
  stageV(0, 0);
  __syncthreads();

  for (int t = 0; t < nt; ++t) {
    int cur = t & 1;
    if (t + 1 < nt) {
      stageK((t + 1) * 64, cur ^ 1);
      stageV((t + 1) * 64, cur ^ 1);
    }
    int s0 = t * 64;
    const bool act0 = !CAUSAL || (s0 < q0 + 64);

    s16x8 kf[4][2];
#pragma unroll
    for (int g = 0; g < 4; g++) {
      kf[g][0] = ld16s(&Ks[cur][0], g * 16 + llo, lhi);
      kf[g][1] = ld16s(&Ks[cur][0], g * 16 + llo, 4 + lhi);
    }

    s16x8 pf[2][2];
#pragma unroll
    for (int s = 0; s < 2; s++) {
      if (s == 0 && !act0) continue;
      f32x4 sacc[4] = {};
#pragma unroll
      for (int g = 0; g < 4; g++) {
        sacc[g] = mfma16(kf[g][0], qf[s][0], sacc[g]);
        sacc[g] = mfma16(kf[g][1], qf[s][1], sacc[g]);
      }
      const int qrow = qr + s * 64;
      const bool diag = CAUSAL && (s0 == q0 + s * 64);
      float sv[16];
      float pmax = -1.0e30f;
#pragma unroll
      for (int g = 0; g < 4; g++)
#pragma unroll
        for (int i = 0; i < 4; i++) {
          float sc = sacc[g][i];
          if (diag) {
            int kv = s0 + g * 16 + lhi * 4 + i;
            if (kv > qrow) sc = -1.0e9f;
          }
          sv[g * 4 + i] = sc;
          pmax = fmaxf(pmax, sc);
        }
      pmax = fmaxf(pmax, __shfl_xor(pmax, 16));
      pmax = fmaxf(pmax, __shfl_xor(pmax, 32));
      if (!__all(pmax - mrun[s] <= 8.0f)) {
        float mnew = fmaxf(mrun[s], pmax);
        float alpha = __expf(mrun[s] - mnew);
        lrun[s] *= alpha;
#pragma unroll
        for (int g = 0; g < 4; g++) {
          oacc[s][g][0] *= alpha; oacc[s][g][1] *= alpha;
          oacc[s][g][2] *= alpha; oacc[s][g][3] *= alpha;
        }
        mrun[s] = mnew;
      }
      float ls = 0.0f;
#pragma unroll
      for (int j = 0; j < 16; j++) {
        float p = __expf(sv[j] - mrun[s]);
        ls += p;
        pf[s][j >> 3][((j >> 2) & 1) * 4 + (j & 3)] = (short)f2b_hw(p);
      }
      ls += __shfl_xor(ls, 16);
      ls += __shfl_xor(ls, 32);
      lrun[s] += ls;
    }

#pragma unroll
    for (int dg = 0; dg < 4; dg++) {
      int row = dg * 16 + llo;
      s16x8 vf0 = ld8s(&Vs[cur][0], row, lhi * 4);
      s16x8 vf1 = ld8s(&Vs[cur][0], row, 32 + lhi * 4);
      if (act0) {
        oacc[0][dg] = mfma16(vf0, pf[0][0], oacc[0][dg]);
        oacc[0][dg] = mfma16(vf1, pf[0][1], oacc[0][dg]);
      }
      oacc[1][dg] = mfma16(vf0, pf[1][0], oacc[1][dg]);
      oacc[1][dg] = mfma16(vf1, pf[1][1], oacc[1][dg]);
    }

    __syncthreads();
  }

#pragma unroll
  for (int s = 0; s < 2; s++) {
    float inv = 1.0f / lrun[s];
    u16* orow = Og + (size_t)(b * TSEQ + qr + s * 64) * DMODEL + h * 64;
#pragma unroll
    for (int dg = 0; dg < 4; dg++) {
      ushort4 st = make_ushort4(f2b_hw(oacc[s][dg][0] * inv), f2b_hw(oacc[s][dg][1] * inv),
                                f2b_hw(oacc[s][dg][2] * inv), f2b_hw(oacc[s][dg][3] * inv));
      *(ushort4*)(orow + dg * 16 + lhi * 4) = st;
    }
  }
}

// ---------- launch ----------

extern "C" void kernel_launch(void* const* d_in, const int* in_sizes, int n_in,
                              void* d_out, int out_size, void* d_ws, size_t ws_size,
                              hipStream_t stream) {
  const float* x      = (const float*)d_in[0];
  const float* memory = (const float*)d_in[1];
  const float* sa_wq = (const float*)d_in[4];  const float* sa_bq = (const float*)d_in[5];
  const float* sa_wk = (const float*)d_in[6];  const float* sa_bk = (const float*)d_in[7];
  const float* sa_wv = (const float*)d_in[8];  const float* sa_bv = (const float*)d_in[9];
  const float* sa_wo = (const float*)d_in[10]; const float* sa_bo = (const float*)d_in[11];
  const float* ca_wq = (const float*)d_in[12]; const float* ca_bq = (const float*)d_in[13];
  const float* ca_wk = (const float*)d_in[14]; const float* ca_bk = (const float*)d_in[15];
  const float* ca_wv = (const float*)d_in[16]; const float* ca_bv = (const float*)d_in[17];
  const float* ca_wo = (const float*)d_in[18]; const float* ca_bo = (const float*)d_in[19];
  const float* ff_w1 = (const float*)d_in[20]; const float* ff_b1 = (const float*)d_in[21];
  const float* ff_w2 = (const float*)d_in[22]; const float* ff_b2 = (const float*)d_in[23];
  const float* ln1_w = (const float*)d_in[24]; const float* ln1_b = (const float*)d_in[25];
  const float* ln2_w = (const float*)d_in[26]; const float* ln2_b = (const float*)d_in[27];
  const float* ln3_w = (const float*)d_in[28]; const float* ln3_b = (const float*)d_in[29];
  float* out = (float*)d_out;

  char* ws = (char*)d_ws;
  const size_t MB = 1u << 20;
  u16* h_bf   = (u16*)(ws + 0 * MB);
  u16* mem_bf = (u16*)(ws + 8 * MB);
  u16* qb     = (u16*)(ws + 16 * MB);   // qb/kb/vb contiguous, 8MB apart
  u16* kb     = (u16*)(ws + 24 * MB);
  u16* vb     = (u16*)(ws + 32 * MB);   // holds V^T [bh][64][1024]
  u16* attnb  = (u16*)(ws + 40 * MB);
  u16* ffmid  = (u16*)(ws + 48 * MB);
  u16* pk     = (u16*)(ws + 16 * MB);   // split-K bf16 partials (reuse qb/kb, 16MB)
  u16* w_sq   = (u16*)(ws + 80 * MB);   // w_sq/w_sk/w_sv contiguous
  u16* w_sk   = (u16*)(ws + 82 * MB);
  u16* w_sv   = (u16*)(ws + 84 * MB);
  u16* w_so   = (u16*)(ws + 86 * MB);
  u16* w_cq   = (u16*)(ws + 88 * MB);   // w_cq/w_ck/w_cv contiguous -> merged cross QKV
  u16* w_ck   = (u16*)(ws + 90 * MB);
  u16* w_cv   = (u16*)(ws + 92 * MB);
  u16* w_co   = (u16*)(ws + 94 * MB);
  u16* w_f1   = (u16*)(ws + 96 * MB);
  u16* w_f2   = (u16*)(ws + 104 * MB);

  F2B fa;
  fa.s[0] = sa_wq; fa.d[0] = w_sq;
  fa.s[1] = sa_wk; fa.d[1] = w_sk;
  fa.s[2] = sa_wv; fa.d[2] = w_sv;
  fa.s[3] = sa_wo; fa.d[3] = w_so;
  fa.s[4] = ca_wq; fa.d[4] = w_cq;
  fa.s[5] = ca_wk; fa.d[5] = w_ck;
  fa.s[6] = ca_wv; fa.d[6] = w_cv;
  fa.s[7] = ca_wo; fa.d[7] = w_co;
  fa.s[8] = ff_w1; fa.d[8] = w_f1;
  fa.s[9] = ff_w2; fa.d[9] = w_f2;
  fa.s[10] = memory; fa.d[10] = mem_bf;
  f2b_all<<<20480, 256, 0, stream>>>(fa);

  // ---- self-attention block ----
  ln_kernel<<<4096, 256, 0, stream>>>(x, ln1_w, ln1_b, h_bf);
  gemm_bt<2, false, false, 0, 2><<<768, 512, 0, stream>>>(
      h_bf, nullptr, w_sq, sa_bq, sa_bk, sa_bv, nullptr, qb, NTOK, 3072, DMODEL, DMODEL, 24);
  attn_kernel<true><<<512, 256, 0, stream>>>(qb, kb, vb, attnb);
  gemm_bt<0, false><<<256, 512, 0, stream>>>(attnb, nullptr, w_so, sa_bo, nullptr, nullptr,
                                             x, out, NTOK, DMODEL, DMODEL, DMODEL, 8);

  // ---- cross-attention block ----
  ln_kernel<<<4096, 256, 0, stream>>>(out, ln2_w, ln2_b, h_bf);
  // merged cross q (A = h_bf) + kv (A = mem_bf) projection: one 768-block dispatch
  gemm_bt<2, false, false, 0, 2><<<768, 512, 0, stream>>>(
      h_bf, mem_bf, w_cq, ca_bq, ca_bk, ca_bv, nullptr, qb, NTOK, 3072, DMODEL, DMODEL, 24);
  attn_kernel<false><<<512, 256, 0, stream>>>(qb, kb, vb, attnb);
  gemm_bt<0, false><<<256, 512, 0, stream>>>(attnb, nullptr, w_co, ca_bo, nullptr, nullptr,
                                             out, out, NTOK, DMODEL, DMODEL, DMODEL, 8);

  // ---- FFN block ----
  ln_kernel<<<4096, 256, 0, stream>>>(out, ln3_w, ln3_b, h_bf);
  gemm256<true><<<256, 512, 0, stream>>>(h_bf, w_f1, ff_b1, ffmid,
                                         NTOK, DFF, DMODEL, DMODEL, 16);
  gemm_bt<4, false, true><<<512, 512, 0, stream>>>(ffmid, nullptr, w_f2, nullptr, nullptr,
                                                   nullptr, nullptr, pk, NTOK, DMODEL, 2048, DFF, 8);
  ff2_reduce<<<4096, 256, 0, stream>>>(pk, ff_b2, out);

  (void)in_sizes; (void)n_in; (void)out_size; (void)ws_size;
}

// Round 16
// 312.334 us; speedup vs baseline: 1.0675x; 1.0270x over previous
//
#include <hip/hip_runtime.h>
#include <hip/hip_bf16.h>

typedef unsigned short u16;
typedef __attribute__((ext_vector_type(4))) float f32x4;
typedef __attribute__((ext_vector_type(8))) short s16x8;
typedef __attribute__((ext_vector_type(4))) short s16x4;
typedef __attribute__((ext_vector_type(8))) __bf16 bf16x8;

#define NTOK 4096
#define DMODEL 1024
#define DFF 4096
#define NH 16
#define TSEQ 1024

#define SBAR() do { asm volatile("" ::: "memory"); __builtin_amdgcn_s_barrier(); asm volatile("" ::: "memory"); } while (0)

// ---------- helpers ----------

__device__ __forceinline__ u16 f2b_hw(float f) {
  union { __bf16 h; u16 u; } cv;
  cv.h = (__bf16)f;
  return cv.u;
}

__device__ __forceinline__ float b2f(u16 u) {
  return __uint_as_float(((unsigned)u) << 16);
}

__device__ __forceinline__ f32x4 mfma16(s16x8 a, s16x8 b, f32x4 c) {
  return __builtin_amdgcn_mfma_f32_16x16x32_bf16((bf16x8)a, (bf16x8)b, c, 0, 0, 0);
}

__device__ __forceinline__ void gload16(const u16* g, u16* l) {
  __builtin_amdgcn_global_load_lds(
      (const __attribute__((address_space(1))) unsigned int*)g,
      (__attribute__((address_space(3))) unsigned int*)l, 16, 0, 0);
}

// natural-layout fragment from a swizzled 64-elem-row LDS tile
__device__ __forceinline__ s16x8 ld8s(const u16* t, int row, int eoff) {
  int rx = row & 7;
  const u16* p1 = t + row * 64 + ((((eoff >> 3) ^ rx) << 3) | (eoff & 7));
  const u16* p2 = t + row * 64 + (((((eoff + 16) >> 3) ^ rx) << 3) | (eoff & 7));
  s16x4 lo = *(const s16x4*)p1;
  s16x4 hi = *(const s16x4*)p2;
  s16x8 r;
  r[0] = lo[0]; r[1] = lo[1]; r[2] = lo[2]; r[3] = lo[3];
  r[4] = hi[0]; r[5] = hi[1]; r[6] = hi[2]; r[7] = hi[3];
  return r;
}

// k-permuted (contiguous 16B, uniform permutation) fragment from swizzled tile
__device__ __forceinline__ s16x8 ld16s(const u16* t, int row, int ch) {
  return *(const s16x8*)(t + row * 64 + ((ch ^ (row & 7)) << 3));
}

// ---------- fused fp32 -> bf16 converts (11 segments, one kernel) ----------

struct F2B {
  const float* s[11];
  u16* d[11];
};

__global__ __launch_bounds__(256) void f2b_all(F2B a) {
  int bid = blockIdx.x;
  int seg, boff;
  if (bid < 8192) { seg = bid >> 10; boff = bid & 1023; }
  else { int j = bid - 8192; seg = 8 + (j >> 12); boff = j & 4095; }
  size_t i = ((size_t)boff * 256 + threadIdx.x) * 4;
  float4 v = *(const float4*)(a.s[seg] + i);
  ushort4 o = make_ushort4(f2b_hw(v.x), f2b_hw(v.y), f2b_hw(v.z), f2b_hw(v.w));
  *(ushort4*)(a.d[seg] + i) = o;
}

// ---------- LayerNorm ----------

__global__ __launch_bounds__(256) void ln_kernel(const float* __restrict__ x,
                                                 const float* __restrict__ w,
                                                 const float* __restrict__ b,
                                                 u16* __restrict__ out) {
  int row = blockIdx.x;
  int t = threadIdx.x;
  const float* xr = x + (size_t)row * DMODEL;
  float4 v = *(const float4*)(xr + t * 4);
  float s = v.x + v.y + v.z + v.w;
#pragma unroll
  for (int off = 1; off < 64; off <<= 1) s += __shfl_xor(s, off);
  __shared__ float red[8];
  int wid = t >> 6, lane = t & 63;
  if (lane == 0) red[wid] = s;
  __syncthreads();
  float mean = (red[0] + red[1] + red[2] + red[3]) * (1.0f / 1024.0f);
  float dx = v.x - mean, dy = v.y - mean, dz = v.z - mean, dw = v.w - mean;
  float ss = dx * dx + dy * dy + dz * dz + dw * dw;
#pragma unroll
  for (int off = 1; off < 64; off <<= 1) ss += __shfl_xor(ss, off);
  if (lane == 0) red[4 + wid] = ss;
  __syncthreads();
  float sst = red[4] + red[5] + red[6] + red[7];
  float inv = 1.0f / (sqrtf(sst / 1023.0f) + 1e-6f);
  float4 wv = *(const float4*)(w + t * 4);
  float4 bv = *(const float4*)(b + t * 4);
  ushort4 o = make_ushort4(f2b_hw(wv.x * dx * inv + bv.x), f2b_hw(wv.y * dy * inv + bv.y),
                           f2b_hw(wv.z * dz * inv + bv.z), f2b_hw(wv.w * dw * inv + bv.w));
  *(ushort4*)(out + (size_t)row * DMODEL + t * 4) = o;
}

// ---------- 256x256x64 8-phase GEMM (T2+T3+T4+T5), bf16 out (+RELU) ----------
// Round-12 proven: 0 bank conflicts, 45.0us on FF1 (vs 48.4 2-phase).

template <bool RELU>
__global__ __launch_bounds__(512, 2) void gemm256(const u16* __restrict__ A,
                                                  const u16* __restrict__ W,
                                                  const float* __restrict__ bias,
                                                  u16* __restrict__ out,
                                                  int M, int N, int K, int ld,
                                                  int gx) {
  __shared__ u16 As[2][2][8192];
  __shared__ u16 Bs[2][2][8192];
  const int nwg = gridDim.x, qch = nwg >> 3, bid = blockIdx.x;
  const int wg = (bid & 7) * qch + (bid >> 3);
  const int bx = wg % gx, by = wg / gx;
  const int m0 = by * 256, n0 = bx * 256;
  const int tid = threadIdx.x;
  const int wid = tid >> 6, lane = tid & 63;
  const int wr = wid >> 2, wc = wid & 3;
  const int lhi = lane >> 4, llo = lane & 15;
  f32x4 acc[8][4] = {};
  const int srow = tid >> 2;
  const int ssw = ((tid & 3) ^ ((srow >> 1) & 3)) << 3;  // pre-swizzled source chunk

  auto unitA = [&](int kt, int kh) {
    const u16* p = A + (size_t)(m0 + srow) * ld + kt * 64 + kh * 32 + ssw;
    gload16(p, &As[kt & 1][kh][tid * 8]);
    gload16(p + (size_t)128 * ld, &As[kt & 1][kh][4096 + tid * 8]);
  };
  auto unitB = [&](int kt, int kh) {
    const u16* p = W + (size_t)(n0 + srow) * ld + kt * 64 + kh * 32 + ssw;
    gload16(p, &Bs[kt & 1][kh][tid * 8]);
    gload16(p + (size_t)128 * ld, &Bs[kt & 1][kh][4096 + tid * 8]);
  };

  s16x8 bf[4];
  auto phase = [&](int d, int ch, int kh, bool loadB, auto stfn, int vm) {
    s16x8 af[4];
#pragma unroll
    for (int fm = 0; fm < 4; fm++) {
      int row = wr * 128 + ch * 64 + fm * 16 + llo;
      af[fm] = *(const s16x8*)(&As[d][kh][row * 32 + ((lhi ^ ((row >> 1) & 3)) << 3)]);
    }
    if (loadB) {
#pragma unroll
      for (int fn = 0; fn < 4; fn++) {
        int row = wc * 64 + fn * 16 + llo;
        bf[fn] = *(const s16x8*)(&Bs[d][kh][row * 32 + ((lhi ^ ((row >> 1) & 3)) << 3)]);
      }
    }
    stfn();
    SBAR();
    __builtin_amdgcn_s_setprio(1);
#pragma unroll
    for (int fm = 0; fm < 4; fm++)
#pragma unroll
      for (int fn = 0; fn < 4; fn++)
        acc[ch * 4 + fm][fn] = mfma16(af[fm], bf[fn], acc[ch * 4 + fm][fn]);
    __builtin_amdgcn_s_setprio(0);
    if (vm == 8) asm volatile("s_waitcnt vmcnt(8)" ::: "memory");
    else if (vm == 4) asm volatile("s_waitcnt vmcnt(4)" ::: "memory");
    else if (vm == 0) asm volatile("s_waitcnt vmcnt(0)" ::: "memory");
    SBAR();
  };

  // prologue: 6 units (t0 full + t1 k0)
  unitA(0, 0); unitB(0, 0); unitA(0, 1); unitB(0, 1); unitA(1, 0); unitB(1, 0);
  asm volatile("s_waitcnt vmcnt(8)" ::: "memory");
  SBAR();

  const int NPAIR = K >> 7;
#pragma unroll 1
  for (int i = 0; i < NPAIR; ++i) {
    const int tb = 2 * i + 1, tc = 2 * i + 2, td = 2 * i + 3;
    const bool nx = (i + 1 < NPAIR);
    phase(0, 0, 0, true,  [&] { unitA(tb, 1); }, -1);
    phase(0, 1, 0, false, [&] { unitB(tb, 1); }, 8);
    phase(0, 1, 1, true,  [&] { if (nx) unitA(tc, 0); }, -1);
    phase(0, 0, 1, false, [&] { if (nx) unitB(tc, 0); }, nx ? 8 : 4);
    phase(1, 0, 0, true,  [&] { if (nx) unitA(tc, 1); }, -1);
    phase(1, 1, 0, false, [&] { if (nx) unitB(tc, 1); }, nx ? 8 : 0);
    phase(1, 1, 1, true,  [&] { if (nx) unitA(td, 0); }, -1);
    phase(1, 0, 1, false, [&] { if (nx) unitB(td, 0); }, nx ? 8 : -1);
  }

#pragma unroll
  for (int ch = 0; ch < 2; ch++)
#pragma unroll
    for (int fm = 0; fm < 4; fm++)
#pragma unroll
      for (int fn = 0; fn < 4; fn++) {
        int r0 = m0 + wr * 128 + ch * 64 + fm * 16 + lhi * 4;
        int c = n0 + wc * 64 + fn * 16 + llo;
        float bv = bias[c];
#pragma unroll
        for (int i2 = 0; i2 < 4; i2++) {
          float v = acc[ch * 4 + fm][fn][i2] + bv;
          if (RELU) v = fmaxf(v, 0.0f);
          out[(size_t)(r0 + i2) * N + c] = f2b_hw(v);
        }
      }
  (void)M;
}

// ---------- 2-phase 512-thread GEMM (proven round-7/10 config) ----------
// MODE 0: fp32 out [M,N] (+resid); MODE 1: bf16 [M,N] (+RELU);
// MODE 2: packed heads (QBUF scaled, VBUF transposed); A2 (optional):
//   block-uniform alternate A for output segments n0 >= 1024 (cross q+kv merge).
// MODE 4 (SPLITK): bf16 partial at outp + half*M*N (no bias/resid).

template <int MODE, bool RELU, bool SPLITK = false, int QBUF = -1, int VBUF = -1>
__global__ __launch_bounds__(512) void gemm_bt(const u16* __restrict__ A,
                                               const u16* __restrict__ A2,
                                               const u16* __restrict__ W,
                                               const float* __restrict__ b0,
                                               const float* __restrict__ b1,
                                               const float* __restrict__ b2,
                                               const float* resid, void* outp,
                                               int M, int N, int K, int ld,
                                               int gx) {
  __shared__ u16 As[2][128 * 64];
  __shared__ u16 Bs[2][128 * 64];
  const int nwg = gridDim.x;
  const int qch = nwg >> 3;
  const int bid = blockIdx.x;
  int wg = (bid & 7) * qch + (bid >> 3);
  int half = 0;
  if (SPLITK) { half = wg & 1; wg >>= 1; }
  const int bx = wg % gx, by = wg / gx;
  const int m0 = by * 128, n0 = bx * 128;
  if (SPLITK) { A += (size_t)half * K; W += (size_t)half * K; }
  if (MODE == 2 && A2 != nullptr && n0 >= 1024) A = A2;  // block-uniform select
  const int tid = threadIdx.x;
  const int wid = tid >> 6, lane = tid & 63;
  const int wr = wid >> 2, wc = wid & 3;
  const int lhi = lane >> 4, llo = lane & 15;
  f32x4 acc[4][2] = {};
  const int sr = tid >> 3, sc = tid & 7;
  const int srcoff = (sc ^ (sr & 7)) << 3;

  auto stage = [&](int kk, int buf) {
    const u16* Ap = A + (size_t)(m0 + sr) * ld + kk + srcoff;
    gload16(Ap, &As[buf][tid * 8]);
    gload16(Ap + (size_t)64 * ld, &As[buf][4096 + tid * 8]);
    const u16* Wp = W + (size_t)(n0 + sr) * ld + kk + srcoff;
    gload16(Wp, &Bs[buf][tid * 8]);
    gload16(Wp + (size_t)64 * ld, &Bs[buf][4096 + tid * 8]);
  };

  stage(0, 0);
  __syncthreads();

  for (int k0 = 0; k0 < K; k0 += 64) {
    int cur = (k0 >> 6) & 1;
    if (k0 + 64 < K) stage(k0 + 64, cur ^ 1);
#pragma unroll
    for (int ks8 = 0; ks8 < 8; ks8 += 4) {
      s16x8 af[4], bfr[2];
#pragma unroll
      for (int f = 0; f < 4; f++) af[f] = ld16s(&As[cur][0], wr * 64 + f * 16 + llo, ks8 + lhi);
#pragma unroll
      for (int g = 0; g < 2; g++) bfr[g] = ld16s(&Bs[cur][0], wc * 32 + g * 16 + llo, ks8 + lhi);
#pragma unroll
      for (int f = 0; f < 4; f++)
#pragma unroll
        for (int g = 0; g < 2; g++) acc[f][g] = mfma16(af[f], bfr[g], acc[f][g]);
    }
    __syncthreads();
  }

#pragma unroll
  for (int fm = 0; fm < 4; fm++) {
#pragma unroll
    for (int fn = 0; fn < 2; fn++) {
      int c = n0 + wc * 32 + fn * 16 + llo;
      const int r0 = m0 + wr * 64 + fm * 16 + lhi * 4;
      if (MODE == 2) {
        int buf = c >> 10, cc = c & 1023;
        int hh = cc >> 6, d = cc & 63;
        int bb = r0 >> 10, t0 = r0 & 1023;
        const float* bias = (buf == 0) ? b0 : ((buf == 1) ? b1 : b2);
        float bv = bias[cc];
        float v4[4];
#pragma unroll
        for (int i = 0; i < 4; i++) {
          float v = acc[fm][fn][i] + bv;
          if (buf == QBUF) v *= 0.125f;
          v4[i] = v;
        }
        if (buf == VBUF) {
          ushort4 st = make_ushort4(f2b_hw(v4[0]), f2b_hw(v4[1]), f2b_hw(v4[2]), f2b_hw(v4[3]));
          *(ushort4*)(&((u16*)outp)[(size_t)buf * 4194304 +
                                    (((size_t)(bb * NH + hh)) * 64 + d) * TSEQ + t0]) = st;
        } else {
#pragma unroll
          for (int i = 0; i < 4; i++)
            ((u16*)outp)[(size_t)buf * 4194304 +
                         (((size_t)(bb * NH + hh)) * TSEQ + t0 + i) * 64 + d] = f2b_hw(v4[i]);
        }
      } else if (MODE == 4) {
#pragma unroll
        for (int i = 0; i < 4; i++)
          ((u16*)outp)[(size_t)half * M * N + (size_t)(r0 + i) * N + c] =
              f2b_hw(acc[fm][fn][i]);
      } else {
        float bv = b0 ? b0[c] : 0.0f;
#pragma unroll
        for (int i = 0; i < 4; i++) {
          int r = r0 + i;
          float v = acc[fm][fn][i] + bv;
          if (resid) v += resid[(size_t)r * N + c];
          if (RELU) v = fmaxf(v, 0.0f);
          if (MODE == 0) {
            ((float*)outp)[(size_t)r * N + c] = v;
          } else {
            ((u16*)outp)[(size_t)r * N + c] = f2b_hw(v);
          }
        }
      }
    }
  }
}

// ---------- split-K reduce (bf16 partials): out += p0 + p1 + bias ----------

__global__ __launch_bounds__(256) void ff2_reduce(const u16* __restrict__ p,
                                                  const float* __restrict__ bias,
                                                  float* __restrict__ out) {
  int row = blockIdx.x, t = threadIdx.x;
  size_t i = (size_t)row * 1024 + t * 4;
  const u16* p1 = p + (size_t)4194304;
  s16x4 a = *(const s16x4*)(p + i);
  s16x4 b = *(const s16x4*)(p1 + i);
  float4 r = *(const float4*)(out + i);
  float4 bv = *(const float4*)(bias + t * 4);
  float4 o = make_float4(b2f((u16)a[0]) + b2f((u16)b[0]) + r.x + bv.x,
                         b2f((u16)a[1]) + b2f((u16)b[1]) + r.y + bv.y,
                         b2f((u16)a[2]) + b2f((u16)b[2]) + r.z + bv.z,
                         b2f((u16)a[3]) + b2f((u16)b[3]) + r.w + bv.w);
  *(float4*)(out + i) = o;
}

// ---------- flash attention: QBLK=64, 1024 blocks (4/CU), 1 strip/wave ----------
// wg = (bid&7)*128 + (bid>>3); bh = wg>>4 (per-XCD bh chunks -> KV L2-local);
// qblk = (wg&15) ^ 15*p, p = (bid>>8)&1. Per-bh p is constant (bijective);
// same-CU block quadruples get complementary (q,15-q) -> causal tiles 17/pair.

template <bool CAUSAL>
__global__ __launch_bounds__(256) void attn_kernel(const u16* __restrict__ Qg,
                                                   const u16* __restrict__ Kg,
                                                   const u16* __restrict__ Vt,
                                                   u16* __restrict__ Og) {
  const int bid = blockIdx.x;
  const int wg = (bid & 7) * 128 + (bid >> 3);
  const int bh = wg >> 4;
  const int qblk = (wg & 15) ^ (CAUSAL ? 15 * ((bid >> 8) & 1) : 0);
  const int b = bh >> 4, h = bh & 15;
  const int q0 = qblk * 64;
  const int tid = threadIdx.x, wid = tid >> 6, lane = tid & 63;
  const int lhi = lane >> 4, llo = lane & 15;
  __shared__ u16 Ks[2][4096];
  __shared__ u16 Vs[2][4096];

  const int qr = q0 + wid * 16 + llo;
  const u16* qp0 = Qg + ((size_t)bh * TSEQ + qr) * 64;
  s16x8 qf0 = *(const s16x8*)(qp0 + 8 * lhi);
  s16x8 qf1 = *(const s16x8*)(qp0 + 8 * (4 + lhi));

  f32x4 oacc[4] = {};
  float mrun = -1.0e30f, lrun = 0.0f;
  const size_t kvb = (size_t)bh * (TSEQ * 64);
  const int nt = CAUSAL ? (qblk + 1) : (TSEQ >> 6);

  const int srow = tid >> 3;
  const int ssw = ((tid & 7) ^ (srow & 7)) << 3;

  auto stageK = [&](int s0, int buf) {
    const u16* kb = Kg + kvb + (size_t)s0 * 64;
    gload16(kb + (size_t)srow * 64 + ssw, &Ks[buf][tid * 8]);
    gload16(kb + (size_t)(32 + srow) * 64 + ssw, &Ks[buf][2048 + tid * 8]);
  };
  auto stageV = [&](int s0, int buf) {
    const u16* vb2 = Vt + kvb + s0;
    gload16(vb2 + (size_t)srow * TSEQ + ssw, &Vs[buf][tid * 8]);
    gload16(vb2 + (size_t)(32 + srow) * TSEQ + ssw, &Vs[buf][2048 + tid * 8]);
  };

  stageK(0, 0);
  stageV(0, 0);
  __syncthreads();

  for (int t = 0; t < nt; ++t) {
    int cur = t & 1;
    if (t + 1 < nt) {
      stageK((t + 1) * 64, cur ^ 1);
      stageV((t + 1) * 64, cur ^ 1);
    }
    int s0 = t * 64;
    const bool diag = CAUSAL && (s0 == q0);

    f32x4 sacc[4] = {};
#pragma unroll
    for (int g = 0; g < 4; g++) {
      int row = g * 16 + llo;
      sacc[g] = mfma16(ld16s(&Ks[cur][0], row, lhi), qf0, sacc[g]);
      sacc[g] = mfma16(ld16s(&Ks[cur][0], row, 4 + lhi), qf1, sacc[g]);
    }

    float sv[16];
    float pmax = -1.0e30f;
#pragma unroll
    for (int g = 0; g < 4; g++)
#pragma unroll
      for (int i = 0; i < 4; i++) {
        float sc = sacc[g][i];
        if (diag) {
          int kv = s0 + g * 16 + lhi * 4 + i;
          if (kv > qr) sc = -1.0e9f;
        }
        sv[g * 4 + i] = sc;
        pmax = fmaxf(pmax, sc);
      }
    pmax = fmaxf(pmax, __shfl_xor(pmax, 16));
    pmax = fmaxf(pmax, __shfl_xor(pmax, 32));
    if (!__all(pmax - mrun <= 8.0f)) {
      float mnew = fmaxf(mrun, pmax);
      float alpha = __expf(mrun - mnew);
      lrun *= alpha;
#pragma unroll
      for (int g = 0; g < 4; g++) {
        oacc[g][0] *= alpha; oacc[g][1] *= alpha;
        oacc[g][2] *= alpha; oacc[g][3] *= alpha;
      }
      mrun = mnew;
    }
    s16x8 pf[2];
    float ls = 0.0f;
#pragma unroll
    for (int j = 0; j < 16; j++) {
      float p = __expf(sv[j] - mrun);
      ls += p;
      pf[j >> 3][((j >> 2) & 1) * 4 + (j & 3)] = (short)f2b_hw(p);
    }
    ls += __shfl_xor(ls, 16);
    ls += __shfl_xor(ls, 32);
    lrun += ls;

#pragma unroll
    for (int dg = 0; dg < 4; dg++) {
      int row = dg * 16 + llo;
      oacc[dg] = mfma16(ld8s(&Vs[cur][0], row, lhi * 4), pf[0], oacc[dg]);
      oacc[dg] = mfma16(ld8s(&Vs[cur][0], row, 32 + lhi * 4), pf[1], oacc[dg]);
    }

    __syncthreads();
  }

  float inv = 1.0f / lrun;
  u16* orow = Og + (size_t)(b * TSEQ + qr) * DMODEL + h * 64;
#pragma unroll
  for (int dg = 0; dg < 4; dg++) {
    ushort4 st = make_ushort4(f2b_hw(oacc[dg][0] * inv), f2b_hw(oacc[dg][1] * inv),
                              f2b_hw(oacc[dg][2] * inv), f2b_hw(oacc[dg][3] * inv));
    *(ushort4*)(orow + dg * 16 + lhi * 4) = st;
  }
}

// ---------- launch ----------

extern "C" void kernel_launch(void* const* d_in, const int* in_sizes, int n_in,
                              void* d_out, int out_size, void* d_ws, size_t ws_size,
                              hipStream_t stream) {
  const float* x      = (const float*)d_in[0];
  const float* memory = (const float*)d_in[1];
  const float* sa_wq = (const float*)d_in[4];  const float* sa_bq = (const float*)d_in[5];
  const float* sa_wk = (const float*)d_in[6];  const float* sa_bk = (const float*)d_in[7];
  const float* sa_wv = (const float*)d_in[8];  const float* sa_bv = (const float*)d_in[9];
  const float* sa_wo = (const float*)d_in[10]; const float* sa_bo = (const float*)d_in[11];
  const float* ca_wq = (const float*)d_in[12]; const float* ca_bq = (const float*)d_in[13];
  const float* ca_wk = (const float*)d_in[14]; const float* ca_bk = (const float*)d_in[15];
  const float* ca_wv = (const float*)d_in[16]; const float* ca_bv = (const float*)d_in[17];
  const float* ca_wo = (const float*)d_in[18]; const float* ca_bo = (const float*)d_in[19];
  const float* ff_w1 = (const float*)d_in[20]; const float* ff_b1 = (const float*)d_in[21];
  const float* ff_w2 = (const float*)d_in[22]; const float* ff_b2 = (const float*)d_in[23];
  const float* ln1_w = (const float*)d_in[24]; const float* ln1_b = (const float*)d_in[25];
  const float* ln2_w = (const float*)d_in[26]; const float* ln2_b = (const float*)d_in[27];
  const float* ln3_w = (const float*)d_in[28]; const float* ln3_b = (const float*)d_in[29];
  float* out = (float*)d_out;

  char* ws = (char*)d_ws;
  const size_t MB = 1u << 20;
  u16* h_bf   = (u16*)(ws + 0 * MB);
  u16* mem_bf = (u16*)(ws + 8 * MB);
  u16* qb     = (u16*)(ws + 16 * MB);   // qb/kb/vb contiguous, 8MB apart
  u16* kb     = (u16*)(ws + 24 * MB);
  u16* vb     = (u16*)(ws + 32 * MB);   // holds V^T [bh][64][1024]
  u16* attnb  = (u16*)(ws + 40 * MB);
  u16* ffmid  = (u16*)(ws + 48 * MB);
  u16* pk     = (u16*)(ws + 16 * MB);   // split-K bf16 partials (reuse qb/kb, 16MB)
  u16* w_sq   = (u16*)(ws + 80 * MB);   // w_sq/w_sk/w_sv contiguous
  u16* w_sk   = (u16*)(ws + 82 * MB);
  u16* w_sv   = (u16*)(ws + 84 * MB);
  u16* w_so   = (u16*)(ws + 86 * MB);
  u16* w_cq   = (u16*)(ws + 88 * MB);   // w_cq/w_ck/w_cv contiguous -> merged cross QKV
  u16* w_ck   = (u16*)(ws + 90 * MB);
  u16* w_cv   = (u16*)(ws + 92 * MB);
  u16* w_co   = (u16*)(ws + 94 * MB);
  u16* w_f1   = (u16*)(ws + 96 * MB);
  u16* w_f2   = (u16*)(ws + 104 * MB);

  F2B fa;
  fa.s[0] = sa_wq; fa.d[0] = w_sq;
  fa.s[1] = sa_wk; fa.d[1] = w_sk;
  fa.s[2] = sa_wv; fa.d[2] = w_sv;
  fa.s[3] = sa_wo; fa.d[3] = w_so;
  fa.s[4] = ca_wq; fa.d[4] = w_cq;
  fa.s[5] = ca_wk; fa.d[5] = w_ck;
  fa.s[6] = ca_wv; fa.d[6] = w_cv;
  fa.s[7] = ca_wo; fa.d[7] = w_co;
  fa.s[8] = ff_w1; fa.d[8] = w_f1;
  fa.s[9] = ff_w2; fa.d[9] = w_f2;
  fa.s[10] = memory; fa.d[10] = mem_bf;
  f2b_all<<<20480, 256, 0, stream>>>(fa);

  // ---- self-attention block ----
  ln_kernel<<<4096, 256, 0, stream>>>(x, ln1_w, ln1_b, h_bf);
  gemm_bt<2, false, false, 0, 2><<<768, 512, 0, stream>>>(
      h_bf, nullptr, w_sq, sa_bq, sa_bk, sa_bv, nullptr, qb, NTOK, 3072, DMODEL, DMODEL, 24);
  attn_kernel<true><<<1024, 256, 0, stream>>>(qb, kb, vb, attnb);
  gemm_bt<0, false><<<256, 512, 0, stream>>>(attnb, nullptr, w_so, sa_bo, nullptr, nullptr,
                                             x, out, NTOK, DMODEL, DMODEL, DMODEL, 8);

  // ---- cross-attention block ----
  ln_kernel<<<4096, 256, 0, stream>>>(out, ln2_w, ln2_b, h_bf);
  // merged cross q (A = h_bf) + kv (A = mem_bf) projection: one 768-block dispatch
  gemm_bt<2, false, false, 0, 2><<<768, 512, 0, stream>>>(
      h_bf, mem_bf, w_cq, ca_bq, ca_bk, ca_bv, nullptr, qb, NTOK, 3072, DMODEL, DMODEL, 24);
  attn_kernel<false><<<1024, 256, 0, stream>>>(qb, kb, vb, attnb);
  gemm_bt<0, false><<<256, 512, 0, stream>>>(attnb, nullptr, w_co, ca_bo, nullptr, nullptr,
                                             out, out, NTOK, DMODEL, DMODEL, DMODEL, 8);

  // ---- FFN block ----
  ln_kernel<<<4096, 256, 0, stream>>>(out, ln3_w, ln3_b, h_bf);
  gemm256<true><<<256, 512, 0, stream>>>(h_bf, w_f1, ff_b1, ffmid,
                                         NTOK, DFF, DMODEL, DMODEL, 16);
  gemm_bt<4, false, true><<<512, 512, 0, stream>>>(ffmid, nullptr, w_f2, nullptr, nullptr,
                                                   nullptr, nullptr, pk, NTOK, DMODEL, 2048, DFF, 8);
  ff2_reduce<<<4096, 256, 0, stream>>>(pk, ff_b2, out);

  (void)in_sizes; (void)n_in; (void)out_size; (void)ws_size;
}

// Round 17
// 307.319 us; speedup vs baseline: 1.0849x; 1.0163x over previous
//
#include <hip/hip_runtime.h>
#include <hip/hip_bf16.h>

typedef unsigned short u16;
typedef __attribute__((ext_vector_type(4))) float f32x4;
typedef __attribute__((ext_vector_type(8))) short s16x8;
typedef __attribute__((ext_vector_type(4))) short s16x4;
typedef __attribute__((ext_vector_type(8))) __bf16 bf16x8;

#define NTOK 4096
#define DMODEL 1024
#define DFF 4096
#define NH 16
#define TSEQ 1024

#define SBAR() do { asm volatile("" ::: "memory"); __builtin_amdgcn_s_barrier(); asm volatile("" ::: "memory"); } while (0)

// ---------- helpers ----------

__device__ __forceinline__ u16 f2b_hw(float f) {
  union { __bf16 h; u16 u; } cv;
  cv.h = (__bf16)f;
  return cv.u;
}

__device__ __forceinline__ float b2f(u16 u) {
  return __uint_as_float(((unsigned)u) << 16);
}

__device__ __forceinline__ f32x4 mfma16(s16x8 a, s16x8 b, f32x4 c) {
  return __builtin_amdgcn_mfma_f32_16x16x32_bf16((bf16x8)a, (bf16x8)b, c, 0, 0, 0);
}

__device__ __forceinline__ void gload16(const u16* g, u16* l) {
  __builtin_amdgcn_global_load_lds(
      (const __attribute__((address_space(1))) unsigned int*)g,
      (__attribute__((address_space(3))) unsigned int*)l, 16, 0, 0);
}

// natural-layout fragment from a swizzled 64-elem-row LDS tile
__device__ __forceinline__ s16x8 ld8s(const u16* t, int row, int eoff) {
  int rx = row & 7;
  const u16* p1 = t + row * 64 + ((((eoff >> 3) ^ rx) << 3) | (eoff & 7));
  const u16* p2 = t + row * 64 + (((((eoff + 16) >> 3) ^ rx) << 3) | (eoff & 7));
  s16x4 lo = *(const s16x4*)p1;
  s16x4 hi = *(const s16x4*)p2;
  s16x8 r;
  r[0] = lo[0]; r[1] = lo[1]; r[2] = lo[2]; r[3] = lo[3];
  r[4] = hi[0]; r[5] = hi[1]; r[6] = hi[2]; r[7] = hi[3];
  return r;
}

// k-permuted (contiguous 16B, uniform permutation) fragment from swizzled tile
__device__ __forceinline__ s16x8 ld16s(const u16* t, int row, int ch) {
  return *(const s16x8*)(t + row * 64 + ((ch ^ (row & 7)) << 3));
}

// ---------- fused fp32 -> bf16 converts (11 segments, one kernel) ----------

struct F2B {
  const float* s[11];
  u16* d[11];
};

__global__ __launch_bounds__(256) void f2b_all(F2B a) {
  int bid = blockIdx.x;
  int seg, boff;
  if (bid < 8192) { seg = bid >> 10; boff = bid & 1023; }
  else { int j = bid - 8192; seg = 8 + (j >> 12); boff = j & 4095; }
  size_t i = ((size_t)boff * 256 + threadIdx.x) * 4;
  float4 v = *(const float4*)(a.s[seg] + i);
  ushort4 o = make_ushort4(f2b_hw(v.x), f2b_hw(v.y), f2b_hw(v.z), f2b_hw(v.w));
  *(ushort4*)(a.d[seg] + i) = o;
}

// ---------- LayerNorm ----------

__global__ __launch_bounds__(256) void ln_kernel(const float* __restrict__ x,
                                                 const float* __restrict__ w,
                                                 const float* __restrict__ b,
                                                 u16* __restrict__ out) {
  int row = blockIdx.x;
  int t = threadIdx.x;
  const float* xr = x + (size_t)row * DMODEL;
  float4 v = *(const float4*)(xr + t * 4);
  float s = v.x + v.y + v.z + v.w;
#pragma unroll
  for (int off = 1; off < 64; off <<= 1) s += __shfl_xor(s, off);
  __shared__ float red[8];
  int wid = t >> 6, lane = t & 63;
  if (lane == 0) red[wid] = s;
  __syncthreads();
  float mean = (red[0] + red[1] + red[2] + red[3]) * (1.0f / 1024.0f);
  float dx = v.x - mean, dy = v.y - mean, dz = v.z - mean, dw = v.w - mean;
  float ss = dx * dx + dy * dy + dz * dz + dw * dw;
#pragma unroll
  for (int off = 1; off < 64; off <<= 1) ss += __shfl_xor(ss, off);
  if (lane == 0) red[4 + wid] = ss;
  __syncthreads();
  float sst = red[4] + red[5] + red[6] + red[7];
  float inv = 1.0f / (sqrtf(sst / 1023.0f) + 1e-6f);
  float4 wv = *(const float4*)(w + t * 4);
  float4 bv = *(const float4*)(b + t * 4);
  ushort4 o = make_ushort4(f2b_hw(wv.x * dx * inv + bv.x), f2b_hw(wv.y * dy * inv + bv.y),
                           f2b_hw(wv.z * dz * inv + bv.z), f2b_hw(wv.w * dw * inv + bv.w));
  *(ushort4*)(out + (size_t)row * DMODEL + t * 4) = o;
}

// ---------- 256x256x64 8-phase GEMM (T2+T3+T4+T5), bf16 out (+RELU) ----------
// Round-12 proven: 0 bank conflicts, 45.0us on FF1 (vs 48.4 2-phase).

template <bool RELU>
__global__ __launch_bounds__(512, 2) void gemm256(const u16* __restrict__ A,
                                                  const u16* __restrict__ W,
                                                  const float* __restrict__ bias,
                                                  u16* __restrict__ out,
                                                  int M, int N, int K, int ld,
                                                  int gx) {
  __shared__ u16 As[2][2][8192];
  __shared__ u16 Bs[2][2][8192];
  const int nwg = gridDim.x, qch = nwg >> 3, bid = blockIdx.x;
  const int wg = (bid & 7) * qch + (bid >> 3);
  const int bx = wg % gx, by = wg / gx;
  const int m0 = by * 256, n0 = bx * 256;
  const int tid = threadIdx.x;
  const int wid = tid >> 6, lane = tid & 63;
  const int wr = wid >> 2, wc = wid & 3;
  const int lhi = lane >> 4, llo = lane & 15;
  f32x4 acc[8][4] = {};
  const int srow = tid >> 2;
  const int ssw = ((tid & 3) ^ ((srow >> 1) & 3)) << 3;  // pre-swizzled source chunk

  auto unitA = [&](int kt, int kh) {
    const u16* p = A + (size_t)(m0 + srow) * ld + kt * 64 + kh * 32 + ssw;
    gload16(p, &As[kt & 1][kh][tid * 8]);
    gload16(p + (size_t)128 * ld, &As[kt & 1][kh][4096 + tid * 8]);
  };
  auto unitB = [&](int kt, int kh) {
    const u16* p = W + (size_t)(n0 + srow) * ld + kt * 64 + kh * 32 + ssw;
    gload16(p, &Bs[kt & 1][kh][tid * 8]);
    gload16(p + (size_t)128 * ld, &Bs[kt & 1][kh][4096 + tid * 8]);
  };

  s16x8 bf[4];
  auto phase = [&](int d, int ch, int kh, bool loadB, auto stfn, int vm) {
    s16x8 af[4];
#pragma unroll
    for (int fm = 0; fm < 4; fm++) {
      int row = wr * 128 + ch * 64 + fm * 16 + llo;
      af[fm] = *(const s16x8*)(&As[d][kh][row * 32 + ((lhi ^ ((row >> 1) & 3)) << 3)]);
    }
    if (loadB) {
#pragma unroll
      for (int fn = 0; fn < 4; fn++) {
        int row = wc * 64 + fn * 16 + llo;
        bf[fn] = *(const s16x8*)(&Bs[d][kh][row * 32 + ((lhi ^ ((row >> 1) & 3)) << 3)]);
      }
    }
    stfn();
    SBAR();
    __builtin_amdgcn_s_setprio(1);
#pragma unroll
    for (int fm = 0; fm < 4; fm++)
#pragma unroll
      for (int fn = 0; fn < 4; fn++)
        acc[ch * 4 + fm][fn] = mfma16(af[fm], bf[fn], acc[ch * 4 + fm][fn]);
    __builtin_amdgcn_s_setprio(0);
    if (vm == 8) asm volatile("s_waitcnt vmcnt(8)" ::: "memory");
    else if (vm == 4) asm volatile("s_waitcnt vmcnt(4)" ::: "memory");
    else if (vm == 0) asm volatile("s_waitcnt vmcnt(0)" ::: "memory");
    SBAR();
  };

  // prologue: 6 units (t0 full + t1 k0)
  unitA(0, 0); unitB(0, 0); unitA(0, 1); unitB(0, 1); unitA(1, 0); unitB(1, 0);
  asm volatile("s_waitcnt vmcnt(8)" ::: "memory");
  SBAR();

  const int NPAIR = K >> 7;
#pragma unroll 1
  for (int i = 0; i < NPAIR; ++i) {
    const int tb = 2 * i + 1, tc = 2 * i + 2, td = 2 * i + 3;
    const bool nx = (i + 1 < NPAIR);
    phase(0, 0, 0, true,  [&] { unitA(tb, 1); }, -1);
    phase(0, 1, 0, false, [&] { unitB(tb, 1); }, 8);
    phase(0, 1, 1, true,  [&] { if (nx) unitA(tc, 0); }, -1);
    phase(0, 0, 1, false, [&] { if (nx) unitB(tc, 0); }, nx ? 8 : 4);
    phase(1, 0, 0, true,  [&] { if (nx) unitA(tc, 1); }, -1);
    phase(1, 1, 0, false, [&] { if (nx) unitB(tc, 1); }, nx ? 8 : 0);
    phase(1, 1, 1, true,  [&] { if (nx) unitA(td, 0); }, -1);
    phase(1, 0, 1, false, [&] { if (nx) unitB(td, 0); }, nx ? 8 : -1);
  }

#pragma unroll
  for (int ch = 0; ch < 2; ch++)
#pragma unroll
    for (int fm = 0; fm < 4; fm++)
#pragma unroll
      for (int fn = 0; fn < 4; fn++) {
        int r0 = m0 + wr * 128 + ch * 64 + fm * 16 + lhi * 4;
        int c = n0 + wc * 64 + fn * 16 + llo;
        float bv = bias[c];
#pragma unroll
        for (int i2 = 0; i2 < 4; i2++) {
          float v = acc[ch * 4 + fm][fn][i2] + bv;
          if (RELU) v = fmaxf(v, 0.0f);
          out[(size_t)(r0 + i2) * N + c] = f2b_hw(v);
        }
      }
  (void)M;
}

// ---------- 2-phase 512-thread GEMM (proven round-7/10 config) ----------
// MODE 0: fp32 out [M,N] (+resid); MODE 1: bf16 [M,N] (+RELU);
// MODE 2: packed heads (QBUF scaled, VBUF transposed); A2 (optional):
//   block-uniform alternate A for output segments n0 >= 1024 (cross q+kv merge).
// MODE 4 (SPLITK): bf16 partial at outp + half*M*N (no bias/resid).
// gx==24: rectangle-balanced XCD chunks (8 rows x 12 cols per XCD, 4x2 XCD
// grid) -> per-XCD fetch 5MB vs 7MB with row-major chunks.

template <int MODE, bool RELU, bool SPLITK = false, int QBUF = -1, int VBUF = -1>
__global__ __launch_bounds__(512) void gemm_bt(const u16* __restrict__ A,
                                               const u16* __restrict__ A2,
                                               const u16* __restrict__ W,
                                               const float* __restrict__ b0,
                                               const float* __restrict__ b1,
                                               const float* __restrict__ b2,
                                               const float* resid, void* outp,
                                               int M, int N, int K, int ld,
                                               int gx) {
  __shared__ u16 As[2][128 * 64];
  __shared__ u16 Bs[2][128 * 64];
  const int nwg = gridDim.x;
  const int qch = nwg >> 3;
  const int bid = blockIdx.x;
  int bx, by, half = 0;
  if (gx == 24 && !SPLITK) {
    const int xcd = bid & 7, c = bid >> 3;  // c in [0,96)
    by = (xcd & 3) * 8 + c / 12;
    bx = (xcd >> 2) * 12 + c % 12;
  } else {
    int wg = (bid & 7) * qch + (bid >> 3);
    if (SPLITK) { half = wg & 1; wg >>= 1; }
    bx = wg % gx; by = wg / gx;
  }
  const int m0 = by * 128, n0 = bx * 128;
  if (SPLITK) { A += (size_t)half * K; W += (size_t)half * K; }
  if (MODE == 2 && A2 != nullptr && n0 >= 1024) A = A2;  // block-uniform select
  const int tid = threadIdx.x;
  const int wid = tid >> 6, lane = tid & 63;
  const int wr = wid >> 2, wc = wid & 3;
  const int lhi = lane >> 4, llo = lane & 15;
  f32x4 acc[4][2] = {};
  const int sr = tid >> 3, sc = tid & 7;
  const int srcoff = (sc ^ (sr & 7)) << 3;

  auto stage = [&](int kk, int buf) {
    const u16* Ap = A + (size_t)(m0 + sr) * ld + kk + srcoff;
    gload16(Ap, &As[buf][tid * 8]);
    gload16(Ap + (size_t)64 * ld, &As[buf][4096 + tid * 8]);
    const u16* Wp = W + (size_t)(n0 + sr) * ld + kk + srcoff;
    gload16(Wp, &Bs[buf][tid * 8]);
    gload16(Wp + (size_t)64 * ld, &Bs[buf][4096 + tid * 8]);
  };

  stage(0, 0);
  __syncthreads();

  for (int k0 = 0; k0 < K; k0 += 64) {
    int cur = (k0 >> 6) & 1;
    if (k0 + 64 < K) stage(k0 + 64, cur ^ 1);
#pragma unroll
    for (int ks8 = 0; ks8 < 8; ks8 += 4) {
      s16x8 af[4], bfr[2];
#pragma unroll
      for (int f = 0; f < 4; f++) af[f] = ld16s(&As[cur][0], wr * 64 + f * 16 + llo, ks8 + lhi);
#pragma unroll
      for (int g = 0; g < 2; g++) bfr[g] = ld16s(&Bs[cur][0], wc * 32 + g * 16 + llo, ks8 + lhi);
#pragma unroll
      for (int f = 0; f < 4; f++)
#pragma unroll
        for (int g = 0; g < 2; g++) acc[f][g] = mfma16(af[f], bfr[g], acc[f][g]);
    }
    __syncthreads();
  }

#pragma unroll
  for (int fm = 0; fm < 4; fm++) {
#pragma unroll
    for (int fn = 0; fn < 2; fn++) {
      int c = n0 + wc * 32 + fn * 16 + llo;
      const int r0 = m0 + wr * 64 + fm * 16 + lhi * 4;
      if (MODE == 2) {
        int buf = c >> 10, cc = c & 1023;
        int hh = cc >> 6, d = cc & 63;
        int bb = r0 >> 10, t0 = r0 & 1023;
        const float* bias = (buf == 0) ? b0 : ((buf == 1) ? b1 : b2);
        float bv = bias[cc];
        float v4[4];
#pragma unroll
        for (int i = 0; i < 4; i++) {
          float v = acc[fm][fn][i] + bv;
          if (buf == QBUF) v *= 0.125f;
          v4[i] = v;
        }
        if (buf == VBUF) {
          ushort4 st = make_ushort4(f2b_hw(v4[0]), f2b_hw(v4[1]), f2b_hw(v4[2]), f2b_hw(v4[3]));
          *(ushort4*)(&((u16*)outp)[(size_t)buf * 4194304 +
                                    (((size_t)(bb * NH + hh)) * 64 + d) * TSEQ + t0]) = st;
        } else {
#pragma unroll
          for (int i = 0; i < 4; i++)
            ((u16*)outp)[(size_t)buf * 4194304 +
                         (((size_t)(bb * NH + hh)) * TSEQ + t0 + i) * 64 + d] = f2b_hw(v4[i]);
        }
      } else if (MODE == 4) {
#pragma unroll
        for (int i = 0; i < 4; i++)
          ((u16*)outp)[(size_t)half * M * N + (size_t)(r0 + i) * N + c] =
              f2b_hw(acc[fm][fn][i]);
      } else {
        float bv = b0 ? b0[c] : 0.0f;
#pragma unroll
        for (int i = 0; i < 4; i++) {
          int r = r0 + i;
          float v = acc[fm][fn][i] + bv;
          if (resid) v += resid[(size_t)r * N + c];
          if (RELU) v = fmaxf(v, 0.0f);
          if (MODE == 0) {
            ((float*)outp)[(size_t)r * N + c] = v;
          } else {
            ((u16*)outp)[(size_t)r * N + c] = f2b_hw(v);
          }
        }
      }
    }
  }
}

// ---------- split-K reduce (bf16 partials): out += p0 + p1 + bias ----------

__global__ __launch_bounds__(256) void ff2_reduce(const u16* __restrict__ p,
                                                  const float* __restrict__ bias,
                                                  float* __restrict__ out) {
  int row = blockIdx.x, t = threadIdx.x;
  size_t i = (size_t)row * 1024 + t * 4;
  const u16* p1 = p + (size_t)4194304;
  s16x4 a = *(const s16x4*)(p + i);
  s16x4 b = *(const s16x4*)(p1 + i);
  float4 r = *(const float4*)(out + i);
  float4 bv = *(const float4*)(bias + t * 4);
  float4 o = make_float4(b2f((u16)a[0]) + b2f((u16)b[0]) + r.x + bv.x,
                         b2f((u16)a[1]) + b2f((u16)b[1]) + r.y + bv.y,
                         b2f((u16)a[2]) + b2f((u16)b[2]) + r.z + bv.z,
                         b2f((u16)a[3]) + b2f((u16)b[3]) + r.w + bv.w);
  *(float4*)(out + i) = o;
}

// ---------- flash attention: QBLK=64, 1024 blocks (4/CU), 1 strip/wave ----------

template <bool CAUSAL>
__global__ __launch_bounds__(256) void attn_kernel(const u16* __restrict__ Qg,
                                                   const u16* __restrict__ Kg,
                                                   const u16* __restrict__ Vt,
                                                   u16* __restrict__ Og) {
  const int bid = blockIdx.x;
  const int wg = (bid & 7) * 128 + (bid >> 3);
  const int bh = wg >> 4;
  const int qblk = (wg & 15) ^ (CAUSAL ? 15 * ((bid >> 8) & 1) : 0);
  const int b = bh >> 4, h = bh & 15;
  const int q0 = qblk * 64;
  const int tid = threadIdx.x, wid = tid >> 6, lane = tid & 63;
  const int lhi = lane >> 4, llo = lane & 15;
  __shared__ u16 Ks[2][4096];
  __shared__ u16 Vs[2][4096];

  const int qr = q0 + wid * 16 + llo;
  const u16* qp0 = Qg + ((size_t)bh * TSEQ + qr) * 64;
  s16x8 qf0 = *(const s16x8*)(qp0 + 8 * lhi);
  s16x8 qf1 = *(const s16x8*)(qp0 + 8 * (4 + lhi));

  f32x4 oacc[4] = {};
  float mrun = -1.0e30f, lrun = 0.0f;
  const size_t kvb = (size_t)bh * (TSEQ * 64);
  const int nt = CAUSAL ? (qblk + 1) : (TSEQ >> 6);

  const int srow = tid >> 3;
  const int ssw = ((tid & 7) ^ (srow & 7)) << 3;

  auto stageK = [&](int s0, int buf) {
    const u16* kb = Kg + kvb + (size_t)s0 * 64;
    gload16(kb + (size_t)srow * 64 + ssw, &Ks[buf][tid * 8]);
    gload16(kb + (size_t)(32 + srow) * 64 + ssw, &Ks[buf][2048 + tid * 8]);
  };
  auto stageV = [&](int s0, int buf) {
    const u16* vb2 = Vt + kvb + s0;
    gload16(vb2 + (size_t)srow * TSEQ + ssw, &Vs[buf][tid * 8]);
    gload16(vb2 + (size_t)(32 + srow) * TSEQ + ssw, &Vs[buf][2048 + tid * 8]);
  };

  stageK(0, 0);
  stageV(0, 0);
  __syncthreads();

  for (int t = 0; t < nt; ++t) {
    int cur = t & 1;
    if (t + 1 < nt) {
      stageK((t + 1) * 64, cur ^ 1);
      stageV((t + 1) * 64, cur ^ 1);
    }
    int s0 = t * 64;
    const bool diag = CAUSAL && (s0 == q0);

    f32x4 sacc[4] = {};
#pragma unroll
    for (int g = 0; g < 4; g++) {
      int row = g * 16 + llo;
      sacc[g] = mfma16(ld16s(&Ks[cur][0], row, lhi), qf0, sacc[g]);
      sacc[g] = mfma16(ld16s(&Ks[cur][0], row, 4 + lhi), qf1, sacc[g]);
    }

    float sv[16];
    float pmax = -1.0e30f;
#pragma unroll
    for (int g = 0; g < 4; g++)
#pragma unroll
      for (int i = 0; i < 4; i++) {
        float sc = sacc[g][i];
        if (diag) {
          int kv = s0 + g * 16 + lhi * 4 + i;
          if (kv > qr) sc = -1.0e9f;
        }
        sv[g * 4 + i] = sc;
        pmax = fmaxf(pmax, sc);
      }
    pmax = fmaxf(pmax, __shfl_xor(pmax, 16));
    pmax = fmaxf(pmax, __shfl_xor(pmax, 32));
    if (!__all(pmax - mrun <= 8.0f)) {
      float mnew = fmaxf(mrun, pmax);
      float alpha = __expf(mrun - mnew);
      lrun *= alpha;
#pragma unroll
      for (int g = 0; g < 4; g++) {
        oacc[g][0] *= alpha; oacc[g][1] *= alpha;
        oacc[g][2] *= alpha; oacc[g][3] *= alpha;
      }
      mrun = mnew;
    }
    s16x8 pf[2];
    float ls = 0.0f;
#pragma unroll
    for (int j = 0; j < 16; j++) {
      float p = __expf(sv[j] - mrun);
      ls += p;
      pf[j >> 3][((j >> 2) & 1) * 4 + (j & 3)] = (short)f2b_hw(p);
    }
    ls += __shfl_xor(ls, 16);
    ls += __shfl_xor(ls, 32);
    lrun += ls;

#pragma unroll
    for (int dg = 0; dg < 4; dg++) {
      int row = dg * 16 + llo;
      oacc[dg] = mfma16(ld8s(&Vs[cur][0], row, lhi * 4), pf[0], oacc[dg]);
      oacc[dg] = mfma16(ld8s(&Vs[cur][0], row, 32 + lhi * 4), pf[1], oacc[dg]);
    }

    __syncthreads();
  }

  float inv = 1.0f / lrun;
  u16* orow = Og + (size_t)(b * TSEQ + qr) * DMODEL + h * 64;
#pragma unroll
  for (int dg = 0; dg < 4; dg++) {
    ushort4 st = make_ushort4(f2b_hw(oacc[dg][0] * inv), f2b_hw(oacc[dg][1] * inv),
                              f2b_hw(oacc[dg][2] * inv), f2b_hw(oacc[dg][3] * inv));
    *(ushort4*)(orow + dg * 16 + lhi * 4) = st;
  }
}

// ---------- launch ----------

extern "C" void kernel_launch(void* const* d_in, const int* in_sizes, int n_in,
                              void* d_out, int out_size, void* d_ws, size_t ws_size,
                              hipStream_t stream) {
  const float* x      = (const float*)d_in[0];
  const float* memory = (const float*)d_in[1];
  const float* sa_wq = (const float*)d_in[4];  const float* sa_bq = (const float*)d_in[5];
  const float* sa_wk = (const float*)d_in[6];  const float* sa_bk = (const float*)d_in[7];
  const float* sa_wv = (const float*)d_in[8];  const float* sa_bv = (const float*)d_in[9];
  const float* sa_wo = (const float*)d_in[10]; const float* sa_bo = (const float*)d_in[11];
  const float* ca_wq = (const float*)d_in[12]; const float* ca_bq = (const float*)d_in[13];
  const float* ca_wk = (const float*)d_in[14]; const float* ca_bk = (const float*)d_in[15];
  const float* ca_wv = (const float*)d_in[16]; const float* ca_bv = (const float*)d_in[17];
  const float* ca_wo = (const float*)d_in[18]; const float* ca_bo = (const float*)d_in[19];
  const float* ff_w1 = (const float*)d_in[20]; const float* ff_b1 = (const float*)d_in[21];
  const float* ff_w2 = (const float*)d_in[22]; const float* ff_b2 = (const float*)d_in[23];
  const float* ln1_w = (const float*)d_in[24]; const float* ln1_b = (const float*)d_in[25];
  const float* ln2_w = (const float*)d_in[26]; const float* ln2_b = (const float*)d_in[27];
  const float* ln3_w = (const float*)d_in[28]; const float* ln3_b = (const float*)d_in[29];
  float* out = (float*)d_out;

  char* ws = (char*)d_ws;
  const size_t MB = 1u << 20;
  u16* h_bf   = (u16*)(ws + 0 * MB);
  u16* mem_bf = (u16*)(ws + 8 * MB);
  u16* qb     = (u16*)(ws + 16 * MB);   // qb/kb/vb contiguous, 8MB apart
  u16* kb     = (u16*)(ws + 24 * MB);
  u16* vb     = (u16*)(ws + 32 * MB);   // holds V^T [bh][64][1024]
  u16* attnb  = (u16*)(ws + 40 * MB);
  u16* ffmid  = (u16*)(ws + 48 * MB);
  u16* pk     = (u16*)(ws + 16 * MB);   // split-K bf16 partials (reuse qb/kb, 16MB)
  u16* w_sq   = (u16*)(ws + 80 * MB);   // w_sq/w_sk/w_sv contiguous
  u16* w_sk   = (u16*)(ws + 82 * MB);
  u16* w_sv   = (u16*)(ws + 84 * MB);
  u16* w_so   = (u16*)(ws + 86 * MB);
  u16* w_cq   = (u16*)(ws + 88 * MB);   // w_cq/w_ck/w_cv contiguous -> merged cross QKV
  u16* w_ck   = (u16*)(ws + 90 * MB);
  u16* w_cv   = (u16*)(ws + 92 * MB);
  u16* w_co   = (u16*)(ws + 94 * MB);
  u16* w_f1   = (u16*)(ws + 96 * MB);
  u16* w_f2   = (u16*)(ws + 104 * MB);

  F2B fa;
  fa.s[0] = sa_wq; fa.d[0] = w_sq;
  fa.s[1] = sa_wk; fa.d[1] = w_sk;
  fa.s[2] = sa_wv; fa.d[2] = w_sv;
  fa.s[3] = sa_wo; fa.d[3] = w_so;
  fa.s[4] = ca_wq; fa.d[4] = w_cq;
  fa.s[5] = ca_wk; fa.d[5] = w_ck;
  fa.s[6] = ca_wv; fa.d[6] = w_cv;
  fa.s[7] = ca_wo; fa.d[7] = w_co;
  fa.s[8] = ff_w1; fa.d[8] = w_f1;
  fa.s[9] = ff_w2; fa.d[9] = w_f2;
  fa.s[10] = memory; fa.d[10] = mem_bf;
  f2b_all<<<20480, 256, 0, stream>>>(fa);

  // ---- self-attention block ----
  ln_kernel<<<4096, 256, 0, stream>>>(x, ln1_w, ln1_b, h_bf);
  gemm_bt<2, false, false, 0, 2><<<768, 512, 0, stream>>>(
      h_bf, nullptr, w_sq, sa_bq, sa_bk, sa_bv, nullptr, qb, NTOK, 3072, DMODEL, DMODEL, 24);
  attn_kernel<true><<<1024, 256, 0, stream>>>(qb, kb, vb, attnb);
  gemm_bt<0, false><<<256, 512, 0, stream>>>(attnb, nullptr, w_so, sa_bo, nullptr, nullptr,
                                             x, out, NTOK, DMODEL, DMODEL, DMODEL, 8);

  // ---- cross-attention block ----
  ln_kernel<<<4096, 256, 0, stream>>>(out, ln2_w, ln2_b, h_bf);
  // merged cross q (A = h_bf) + kv (A = mem_bf) projection: one 768-block dispatch
  gemm_bt<2, false, false, 0, 2><<<768, 512, 0, stream>>>(
      h_bf, mem_bf, w_cq, ca_bq, ca_bk, ca_bv, nullptr, qb, NTOK, 3072, DMODEL, DMODEL, 24);
  attn_kernel<false><<<1024, 256, 0, stream>>>(qb, kb, vb, attnb);
  gemm_bt<0, false><<<256, 512, 0, stream>>>(attnb, nullptr, w_co, ca_bo, nullptr, nullptr,
                                             out, out, NTOK, DMODEL, DMODEL, DMODEL, 8);

  // ---- FFN block ----
  ln_kernel<<<4096, 256, 0, stream>>>(out, ln3_w, ln3_b, h_bf);
  gemm256<true><<<256, 512, 0, stream>>>(h_bf, w_f1, ff_b1, ffmid,
                                         NTOK, DFF, DMODEL, DMODEL, 16);
  gemm_bt<4, false, true><<<512, 512, 0, stream>>>(ffmid, nullptr, w_f2, nullptr, nullptr,
                                                   nullptr, nullptr, pk, NTOK, DMODEL, 2048, DFF, 8);
  ff2_reduce<<<4096, 256, 0, stream>>>(pk, ff_b2, out);

  (void)in_sizes; (void)n_in; (void)out_size; (void)ws_size;
}